// Round 3
// baseline (539.021 us; speedup 1.0000x reference)
//
#include <hip/hip_runtime.h>
#include <stdint.h>

#define B_   32
#define L_   512
#define DT_  4
#define NT_  20
#define SMP_ 50
#define H_   132
#define HPAD 144      // padded feature rows (9 n-tiles of 16)
#define KSTR 136      // bf16 W-image k-stride (shorts)
#define CSTR 148      // clds float stride
#define KCH  5        // 5 k-chunks of 32 (K padded 132 -> 160)
#define NTIL 9
#define WBF_N (HPAD*KSTR)      // 19584 shorts
#define ITILE 16      // i-rows per block
#define SCSTR 520     // score-row stride (shorts)
#define HIDS  136     // hid row stride (floats)
#define HNLS  160     // hn LDS row stride (shorts)
#define WDROW 160     // [Win;Wpred] image rows (152 used)
#define NTIL3 10      // decoder n-tiles

typedef float  float4v __attribute__((ext_vector_type(4)));
typedef short  short8  __attribute__((ext_vector_type(8)));
typedef unsigned int uint4v __attribute__((ext_vector_type(4)));

#if __has_builtin(__builtin_rotateleft32)
#define ROTL(x,r) __builtin_rotateleft32((x),(r))
#elif __has_builtin(__builtin_amdgcn_alignbit)
#define ROTL(x,r) __builtin_amdgcn_alignbit((x),(x),32u-(r))
#else
#define ROTL(x,r) (((x)<<(r))|((x)>>(32u-(r))))
#endif

// ---------------- threefry2x32, key=(0,42), JAX partitionable 32-bit path ------------
// bits[f] = o0 ^ o1 of threefry2x32((0,42), ctr=(0,f))  [verified R5-R12]
__device__ __forceinline__ uint32_t tfpair(uint32_t fa, uint32_t fb){
  const uint32_t ks1 = 42u;
  const uint32_t ks2 = 0x1BD11BDAu ^ 42u;
  uint32_t a0 = 0u, b0 = 0u, a1 = fa + ks1, b1 = fb + ks1;
#define TFR(r) a0+=a1; b0+=b1; a1=ROTL(a1,(r)); b1=ROTL(b1,(r)); a1^=a0; b1^=b0;
  TFR(13) TFR(15) TFR(26) TFR(6)
  a0+=ks1; a1+=ks2+1u; b0+=ks1; b1+=ks2+1u;
  TFR(17) TFR(29) TFR(16) TFR(24)
  a0+=ks2; a1+=2u;     b0+=ks2; b1+=2u;       // ks0+2
  TFR(13) TFR(15) TFR(26) TFR(6)
  a1+=ks1+3u;          b1+=ks1+3u;            // x0+=ks0 (0)
  TFR(17) TFR(29) TFR(16) TFR(24)
  a0+=ks1; a1+=ks2+4u; b0+=ks1; b1+=ks2+4u;
  TFR(13) TFR(15) TFR(26) TFR(6)
  a0+=ks2; a1+=5u;     b0+=ks2; b1+=5u;       // ks0+5
#undef TFR
  uint32_t Ya = ((a0 ^ a1) >> 9) + 0x3f808000u;   // bf16 bits in [31:16], RHU rounding
  uint32_t Yb = ((b0 ^ b1) >> 9) + 0x3f808000u;
#if __has_builtin(__builtin_amdgcn_perm)
  return __builtin_amdgcn_perm(Ya, Yb, 0x03020706u);  // {Yb.hi16, Ya.hi16}
#else
  return (Yb & 0xffff0000u) | (Ya >> 16);
#endif
}

__device__ __forceinline__ float softplus_fast(float x){
  return fmaxf(x,0.f) + __logf(1.f + __expf(-fabsf(x)));
}

__device__ __forceinline__ float softplus_f(float x){
  return fmaxf(x,0.f) + log1pf(expf(-fabsf(x)));
}

__device__ __forceinline__ short f2bf(float f){   // fp32 -> bf16 RNE
  uint32_t u = __float_as_uint(f);
  u += 0x7fffu + ((u>>16)&1u);
  return (short)(u>>16);
}

__device__ __forceinline__ float bf_round(float f){   // fp32 -> bf16 -> fp32
  uint32_t u = __float_as_uint(f);
  u += 0x7fffu + ((u>>16)&1u);
  u &= 0xffff0000u;
  return __uint_as_float(u);
}

// ---------------- K0: embeddings -> transposed bf16 hvT image (coalesced) -----------
__global__ __launch_bounds__(256) void k0_embed(
    const int* __restrict__ etype, const float* __restrict__ etime,
    const float* __restrict__ Wt,  const float* __restrict__ temb,
    const float* __restrict__ Wg,  const float* __restrict__ Wl,
    const float* __restrict__ Wn,  const float* __restrict__ Win,
    const float* __restrict__ Wpred,
    uint16_t* __restrict__ hvT, float* __restrict__ sc4,
    uint16_t* __restrict__ wbf, uint16_t* __restrict__ wd, float* __restrict__ rs){
  int blk = blockIdx.x, tid = threadIdx.x;
  if (blk < 128){
    __shared__ __align__(16) uint16_t tile[HPAD*128];   // 36864 B
    __shared__ float tvec[128];
    int b = blk >> 2, l0 = (blk & 3)*128;
    int base = b*L_ + l0;
    if (tid < 128) tvec[tid] = etime[base + tid];
    __syncthreads();
    const float M = -0.07195578414202429f;  // -ln(10000)/128
    for (int rep = 0; rep < 32; ++rep){
      int idx = rep*256 + tid;
      int k = idx >> 7, p = idx & 127;
      float dterm = __expf((float)(2*k) * M);
      float ang = (float)(l0 + p) * dterm + tvec[p] * Wt[k];
      float sv, cv;
      sincosf(ang, &sv, &cv);
      tile[k*128 + p]      = (uint16_t)f2bf(sv);
      tile[(64+k)*128 + p] = (uint16_t)f2bf(cv);
    }
    for (int rep = 0; rep < 8; ++rep){
      int idx = rep*256 + tid;
      int r = 128 + (idx >> 7), p = idx & 127;
      uint16_t v = 0;
      if (r < 132){
        int et = etype[base + p];
        v = (uint16_t)f2bf(temb[et*4 + (r-128)]);
      }
      tile[r*128 + p] = v;
    }
    if (tid < 128){
      int bl = base + tid;
      int et = etype[bl];
      float t0 = temb[et*4+0], t1 = temb[et*4+1], t2 = temb[et*4+2], t3 = temb[et*4+3];
      sc4[bl*4+0] = t0*Wg[0]+t1*Wg[1]+t2*Wg[2]+t3*Wg[3];  // dg  (j-side)
      sc4[bl*4+1] = t0*Wg[4]+t1*Wg[5]+t2*Wg[6]+t3*Wg[7];  // dg2 (i-side)
      sc4[bl*4+2] = t0*Wl[0]+t1*Wl[1]+t2*Wl[2]+t3*Wl[3];  // dl
      sc4[bl*4+3] = t0*Wl[4]+t1*Wl[5]+t2*Wl[6]+t3*Wl[7];  // dl2
    }
    __syncthreads();
    for (int pass = 0; pass < 9; ++pass){
      int r = pass*16 + (tid>>4);
      int c = tid & 15;
      ((uint4v*)(hvT + ((size_t)b*HPAD + r)*L_ + l0))[c] = ((const uint4v*)(tile + r*128))[c];
    }
  } else {
    int pb = blk - 128;                // 0..18
    if (pb < 9){                       // W_noise bf16 image + rowsum(bf16 W)
      for (int e = tid; e < 16*KSTR; e += 256){
        int r = e / KSTR, k = e - r*KSTR;
        int n = pb*16 + r;
        uint16_t v = 0;
        if (n < H_ && k < H_) v = (uint16_t)f2bf(Wn[n*H_ + k]);
        wbf[n*KSTR + k] = v;
      }
      if (tid < 16){
        int n = pb*16 + tid;
        if (n < H_){
          float s = 0.f;
          const float* row = Wn + (size_t)n*H_;
          #pragma unroll 4
          for (int k = 0; k < H_; ++k) s += bf_round(row[k]);
          rs[n] = s;
        }
      }
    } else {                           // [Win; Wpred] bf16 image
      int rb = pb - 9;                 // 0..9
      for (int e = tid; e < 16*KSTR; e += 256){
        int r = e / KSTR, k = e - r*KSTR;
        int n = rb*16 + r;
        uint16_t v = 0;
        if (k < H_){
          if (n < H_)          v = (uint16_t)f2bf(Win[n*H_ + k]);
          else if (n < H_+NT_) v = (uint16_t)f2bf(Wpred[(n-H_)*H_ + k]);
        }
        wd[n*KSTR + k] = v;
      }
    }
  }
}

// ---------------- K1F: fused attention + LN + decoder + GAN sampler ----------------
// R14: fuse k1+k4.  R15: launch_bounds arg semantics on this toolchain:
//   cap = 512/(2*arg)  (arg acts as blocks/CU for 512-thread blocks):
//   arg=6 -> VGPR 40 (spill disaster), arg=2 -> VGPR 128 (no spill but only
//   2 blocks/CU: 16 waves, VALUBusy 68.9%, 377us).
// R16: arg=3 -> cap 85 VGPR -> 3 blocks/CU (LDS limit) = 24 waves/CU, same
//   residency as the 92.7%-busy split k4. Pressure trimmed to fit 85:
//   phase A2 prefetch depth 8->4 (latency now hidden by co-resident blocks'
//   phase B), softmax rewritten two-pass (kills ex[20] array).
//
// LDS plan (51,904 B -> 3 blocks/CU):
//   [0 , 39168) U: phase A = scb(16640)|jt|jg|jl(6144)|hid(8704)|hnl(5120)
//                  phase B = Wlds(39168)   (staged after decoder, all A-bufs dead)
//   [39168,48640) clds[16][148]   [48640,49920) logit[16][20]
//   [49920,50496) wtl[144]        [50496,51072) rsl[144]
//   [51072,51584) part[8][16]     [51584,51904) rt/rg/rl/mur/rsr
__global__ __launch_bounds__(512, 3) void k1_fused(
    const float* __restrict__ etime, const float* __restrict__ sc4,
    const uint16_t* __restrict__ hvT, const uint16_t* __restrict__ wd,
    const uint16_t* __restrict__ wbf, const float* __restrict__ bgp,
    const float* __restrict__ blp, const float* __restrict__ gamma,
    const float* __restrict__ beta, const float* __restrict__ wt,
    const float* __restrict__ rs, float* __restrict__ outp){
  __shared__ __align__(16) uint8_t smem[51904];
  uint16_t* scb  = (uint16_t*)smem;                 // [16][520]
  float*    jt   = (float*)(smem + 16640);
  float*    jg   = (float*)(smem + 18688);
  float*    jl   = (float*)(smem + 20736);
  float*    hid  = (float*)(smem + 22784);          // [16][136]
  uint16_t* hnl  = (uint16_t*)(smem + 31488);       // [16][160]
  uint16_t* Wlds = (uint16_t*)smem;                 // phase B alias [144][136]
  float*    clds = (float*)(smem + 39168);          // [16][148]
  float*    logit= (float*)(smem + 48640);          // [16][20]
  float*    wtl  = (float*)(smem + 49920);          // [144]
  float*    rsl  = (float*)(smem + 50496);          // [144]
  float*    part = (float*)(smem + 51072);          // [8][16]
  float*    rt   = (float*)(smem + 51584);
  float*    rg   = (float*)(smem + 51648);
  float*    rl   = (float*)(smem + 51712);
  float*    mur  = (float*)(smem + 51776);
  float*    rsr  = (float*)(smem + 51840);

  int i0 = blockIdx.x*ITILE, b = blockIdx.y, base = b*L_;
  int bl0 = base + i0;
  int tid = threadIdx.x;
  int wave = tid>>6, lane = tid&63, q = lane>>4, col = lane&15;
  float bg = bgp[0], blv = blp[0];

  // ---- stage params ----
  for (int j = tid; j < L_; j += 512){
    jt[j] = etime[base+j];
    jg[j] = sc4[(base+j)*4+0];
    jl[j] = sc4[(base+j)*4+2];
  }
  if (tid < ITILE){
    rt[tid] = etime[bl0+tid];
    rg[tid] = sc4[(bl0+tid)*4+1];
    rl[tid] = sc4[(bl0+tid)*4+3];
  }
  if (tid >= 256 && tid < 256+HPAD){
    int n = tid - 256;
    wtl[n] = (n < H_) ? wt[n] : 0.f;
    rsl[n] = (n < H_) ? rs[n] : 0.f;
  }
  __syncthreads();

  // ---- phase A1: score tile ----
  for (int e = tid; e < ITILE*L_; e += 512){
    int r = e >> 9, j = e & (L_-1);
    float v = 0.f;
    if (j < i0 + r){
      float gate = __frcp_rn(1.f + __expf(-(jg[j] + rg[r] + bg)));
      float ls   = softplus_fast(jl[j] + rl[r] + blv) + 1e-6f;
      float d    = rt[r] - jt[j];
      float t2   = 2.f*ls*ls;
      v = gate * t2 * __frcp_rn(t2 + d*d);
    }
    scb[r*SCSTR + j] = (uint16_t)f2bf(v);
  }
  __syncthreads();

  // ---- phase A2: hidden[16][H] = scores @ hv (8 waves; 4x4 kt prefetch) ----
  for (int nt = wave; nt < NTIL; nt += 8){
    int n = nt*16 + col;
    const uint16_t* bT = hvT + ((size_t)b*HPAD + n)*L_;   // pad rows zero
    float4v acc = {0.f,0.f,0.f,0.f};
    #pragma unroll
    for (int quar = 0; quar < 4; ++quar){
      short8 bfr[4];
      #pragma unroll
      for (int kt = 0; kt < 4; ++kt)
        bfr[kt] = *(const short8*)&bT[(quar*4+kt)*32 + q*8];
      #pragma unroll
      for (int kt = 0; kt < 4; ++kt){
        short8 af = *(const short8*)&scb[col*SCSTR + (quar*4+kt)*32 + q*8];
        acc = __builtin_amdgcn_mfma_f32_16x16x32_bf16(af, bfr[kt], acc, 0, 0, 0);
      }
    }
    if (n < H_){
      #pragma unroll
      for (int rr = 0; rr < 4; ++rr)
        hid[(q*4+rr)*HIDS + n] = acc[rr];    // C/D: row=q*4+rr, col=n
    }
  }
  __syncthreads();

  // ---- phase A3: LayerNorm (8 waves x 2 rows) ----
  #pragma unroll
  for (int rr = 0; rr < 2; ++rr){
    int r = wave*2 + rr;
    float x0 = hid[r*HIDS + lane];
    float x1 = hid[r*HIDS + 64 + lane];
    float x2 = (lane<4) ? hid[r*HIDS + 128 + lane] : 0.f;
    float s1 = x0+x1+x2, s2 = x0*x0+x1*x1+x2*x2;
    #pragma unroll
    for (int m=32; m; m>>=1){ s1 += __shfl_xor(s1, m, 64); s2 += __shfl_xor(s2, m, 64); }
    if (lane == 0){
      float mu = s1 * (1.f/132.f);
      float var = s2 * (1.f/132.f) - mu*mu;
      mur[r] = mu; rsr[r] = rsqrtf(var + 1e-6f);
    }
  }
  __syncthreads();
  if (tid < HNLS){
    if (tid < H_){
      float g = gamma[tid], be = beta[tid];
      #pragma unroll 4
      for (int r = 0; r < ITILE; ++r)
        hnl[r*HNLS + tid] = (uint16_t)f2bf((hid[r*HIDS+tid]-mur[r])*rsr[r]*g + be);
    } else {
      #pragma unroll 4
      for (int r = 0; r < ITILE; ++r) hnl[r*HNLS + tid] = 0;
    }
  }
  __syncthreads();

  // ---- phase A4: decoder hn(16x132) @ wd(152x132)^T -> clds(-rs) + logits ----
  {
    short8 afr[KCH];
    #pragma unroll
    for (int kc = 0; kc < KCH; ++kc)
      afr[kc] = *(const short8*)&hnl[col*HNLS + kc*32 + q*8];   // A[m=col][k]
    for (int nt = wave; nt < NTIL3; nt += 8){
      float4v acc = {0.f,0.f,0.f,0.f};
      const short8* bp = (const short8*)&wd[(nt*16+col)*KSTR];
      #pragma unroll
      for (int kc = 0; kc < KCH; ++kc){
        // kc=4,q>0 reads past wd row end: A zero at k>=132 -- harmless
        short8 bfr = bp[kc*4 + q];
        acc = __builtin_amdgcn_mfma_f32_16x16x32_bf16(afr[kc], bfr, acc, 0, 0, 0);
      }
      int n = nt*16 + col;
      #pragma unroll
      for (int rr = 0; rr < 4; ++rr){
        int lr = q*4 + rr;
        if (n < H_)            clds[lr*CSTR + n] = acc[rr] - rsl[n];
        else if (n < H_+NT_)   logit[lr*NT_ + (n-H_)] = acc[rr];
      }
    }
    if (tid < 256){                      // zero-pad clds cols 132..147
      int m = tid >> 4, c = H_ + (tid & 15);
      clds[m*CSTR + c] = 0.f;
    }
  }
  __syncthreads();

  // ---- stage W_noise over dead phase-A buffers; softmax logits (two-pass) ----
  {
    const uint4v* g = (const uint4v*)wbf;
    uint4v* l = (uint4v*)Wlds;
    for (int idx = tid; idx < WBF_N/8; idx += 512) l[idx] = g[idx];
  }
  if (tid < ITILE){
    float mx = -1e30f;
    #pragma unroll
    for (int j=0;j<NT_;++j) mx = fmaxf(mx, logit[tid*NT_+j]);
    float ssum = 0.f;
    #pragma unroll
    for (int j=0;j<NT_;++j) ssum += __expf(logit[tid*NT_+j]-mx);
    float inv = __frcp_rn(ssum);
    #pragma unroll
    for (int j=0;j<NT_;++j)
      outp[(size_t)(B_*L_) + (size_t)(bl0+tid)*NT_ + j] = __expf(logit[tid*NT_+j]-mx)*inv;
  }
  __syncthreads();

  // ---- phase B: GAN sampler, wave w owns samples {w, w+8, ...} ----
  float msum0=0.f, msum1=0.f, msum2=0.f, msum3=0.f;
  uint32_t fb_l = (uint32_t)(bl0 + col)*(uint32_t)(SMP_*H_);
  for (int s = wave; s < SMP_; s += 8){
    uint32_t fbase = fb_l + (uint32_t)s*(uint32_t)H_;
    uint32_t fbq = fbase + (uint32_t)(q*8);
    uint4v afu[KCH];
    #pragma unroll
    for (int kc = 0; kc < 4; ++kc){
      #pragma unroll
      for (int t = 0; t < 4; ++t)
        afu[kc][t] = tfpair(fbq + (uint32_t)(kc*32 + 2*t),
                            fbq + (uint32_t)(kc*32 + 2*t + 1));
    }
    {   // tail features 128..131: one full-wave stream (q0:128/129, q1:130/131)
      uint32_t ft = fbase + 128u + (uint32_t)((q & 1)*2);
      uint32_t w  = tfpair(ft, ft + 1u);
      uint32_t wo = (uint32_t)__shfl_xor((int)w, 16, 64);
      uint4v a4 = {0u,0u,0u,0u};
      if (q == 0){ a4[0] = w; a4[1] = wo; }
      afu[4] = a4;
    }
    float racc0=0.f, racc1=0.f, racc2=0.f, racc3=0.f;
    for (int nt = 0; nt < NTIL; ++nt){
      float4v acc = {0.f,0.f,0.f,0.f};
      const short8* bp = (const short8*)&Wlds[(nt*16+col)*KSTR];
      #pragma unroll
      for (int kc = 0; kc < KCH; ++kc){
        short8 bfr = bp[kc*4 + q];
        acc = __builtin_amdgcn_mfma_f32_16x16x32_bf16(
                 __builtin_bit_cast(short8, afu[kc]), bfr, acc, 0, 0, 0);
      }
      int n = nt*16 + col;
      float wv = wtl[n];
      const float* cb = &clds[(q*4)*CSTR + n];
      racc0 += fmaxf(acc[0] + cb[0*CSTR], 0.f)*wv;
      racc1 += fmaxf(acc[1] + cb[1*CSTR], 0.f)*wv;
      racc2 += fmaxf(acc[2] + cb[2*CSTR], 0.f)*wv;
      racc3 += fmaxf(acc[3] + cb[3*CSTR], 0.f)*wv;
    }
    #pragma unroll
    for (int m = 1; m < 16; m <<= 1){
      racc0 += __shfl_xor(racc0, m, 64);
      racc1 += __shfl_xor(racc1, m, 64);
      racc2 += __shfl_xor(racc2, m, 64);
      racc3 += __shfl_xor(racc3, m, 64);
    }
    msum0 += softplus_f(racc0);
    msum1 += softplus_f(racc1);
    msum2 += softplus_f(racc2);
    msum3 += softplus_f(racc3);
  }
  if (col == 0){
    part[wave*16 + q*4 + 0] = 0.02f * msum0;
    part[wave*16 + q*4 + 1] = 0.02f * msum1;
    part[wave*16 + q*4 + 2] = 0.02f * msum2;
    part[wave*16 + q*4 + 3] = 0.02f * msum3;
  }
  __syncthreads();
  if (tid < ITILE){
    float v = 0.f;
    #pragma unroll
    for (int w = 0; w < 8; ++w) v += part[w*16 + tid];
    outp[bl0 + tid] = v;       // sole writer: direct store, no atomic
  }
}

// ---------------- launch ----------------
extern "C" void kernel_launch(void* const* d_in, const int* in_sizes, int n_in,
                              void* d_out, int out_size, void* d_ws, size_t ws_size,
                              hipStream_t stream){
  const int*   etype = (const int*)  d_in[0];
  const float* etime = (const float*)d_in[1];
  const float* Wt    = (const float*)d_in[3];
  const float* temb  = (const float*)d_in[4];
  const float* Wg    = (const float*)d_in[5];
  const float* bgp   = (const float*)d_in[6];
  const float* Wl    = (const float*)d_in[7];
  const float* blp   = (const float*)d_in[8];
  const float* gamma = (const float*)d_in[9];
  const float* beta  = (const float*)d_in[10];
  const float* Win   = (const float*)d_in[11];
  const float* Wn    = (const float*)d_in[12];
  const float* wtm   = (const float*)d_in[13];
  const float* Wpred = (const float*)d_in[14];
  float* out = (float*)d_out;

  uint16_t* hvT   = (uint16_t*)d_ws;                        // 32*144*512 shorts
  float*    sc4   = (float*)(hvT + (size_t)B_*HPAD*L_);     // 16384*4 floats
  float*    rs    = sc4 + (size_t)16384*4;                  // 132 (+pad to 256)
  uint16_t* wbf   = (uint16_t*)(rs + 256);                  // HPAD*KSTR shorts
  uint16_t* wd    = wbf + (size_t)WBF_N;                    // WDROW*KSTR shorts

  k0_embed <<<dim3(147),   dim3(256), 0, stream>>>(etype, etime, Wt, temb, Wg, Wl,
                                                   Wn, Win, Wpred, hvT, sc4, wbf, wd, rs);
  k1_fused <<<dim3(32,32), dim3(512), 0, stream>>>(etime, sc4, hvT, wd, wbf, bgp, blp,
                                                   gamma, beta, wtm, rs, out);
}

// Round 4
// 530.537 us; speedup vs baseline: 1.0160x; 1.0160x over previous
//
#include <hip/hip_runtime.h>
#include <stdint.h>

#define B_   32
#define L_   512
#define DT_  4
#define NT_  20
#define SMP_ 50
#define H_   132
#define HPAD 144      // padded feature rows (9 n-tiles of 16)
#define KSTR 136      // bf16 W-image k-stride (shorts) -- wd (k1 decoder)
#define KSTR4 140     // k4 W_noise image k-stride (shorts): 70 dwords == 6 mod 32 -> <=2-way LDS conflict
#define CSTR 148      // k4 clds float stride
#define KCH  5        // 5 k-chunks of 32 (K padded 132 -> 160)
#define NTIL 9
#define WBF_N4 (HPAD*KSTR4)    // 20160 shorts (40320 B)
#define ITILE 16      // k1 i-rows per block
#define SCSTR 520     // k1 score-row stride (shorts)
#define HIDS  136     // k1 hid row stride (floats)
#define HNLS  160     // k1 fused-decoder hn LDS row stride (shorts)
#define WDROW 160     // [Win;Wpred] image rows (152 used)
#define NTIL3 10      // decoder n-tiles

typedef float  float4v __attribute__((ext_vector_type(4)));
typedef short  short8  __attribute__((ext_vector_type(8)));
typedef unsigned int uint4v __attribute__((ext_vector_type(4)));

#if __has_builtin(__builtin_rotateleft32)
#define ROTL(x,r) __builtin_rotateleft32((x),(r))
#elif __has_builtin(__builtin_amdgcn_alignbit)
#define ROTL(x,r) __builtin_amdgcn_alignbit((x),(x),32u-(r))
#else
#define ROTL(x,r) (((x)<<(r))|((x)>>(32u-(r))))
#endif

// ---------------- threefry2x32, key=(0,42), JAX partitionable 32-bit path ------------
// bits[f] = o0 ^ o1 of threefry2x32((0,42), ctr=(0,f))  [verified R5-R12]
__device__ __forceinline__ uint32_t tfpair(uint32_t fa, uint32_t fb){
  const uint32_t ks1 = 42u;
  const uint32_t ks2 = 0x1BD11BDAu ^ 42u;
  uint32_t a0 = 0u, b0 = 0u, a1 = fa + ks1, b1 = fb + ks1;
#define TFR(r) a0+=a1; b0+=b1; a1=ROTL(a1,(r)); b1=ROTL(b1,(r)); a1^=a0; b1^=b0;
  TFR(13) TFR(15) TFR(26) TFR(6)
  a0+=ks1; a1+=ks2+1u; b0+=ks1; b1+=ks2+1u;
  TFR(17) TFR(29) TFR(16) TFR(24)
  a0+=ks2; a1+=2u;     b0+=ks2; b1+=2u;       // ks0+2
  TFR(13) TFR(15) TFR(26) TFR(6)
  a1+=ks1+3u;          b1+=ks1+3u;            // x0+=ks0 (0)
  TFR(17) TFR(29) TFR(16) TFR(24)
  a0+=ks1; a1+=ks2+4u; b0+=ks1; b1+=ks2+4u;
  TFR(13) TFR(15) TFR(26) TFR(6)
  a0+=ks2; a1+=5u;     b0+=ks2; b1+=5u;       // ks0+5
#undef TFR
  uint32_t Ya = ((a0 ^ a1) >> 9) + 0x3f808000u;   // bf16 bits in [31:16], RHU rounding
  uint32_t Yb = ((b0 ^ b1) >> 9) + 0x3f808000u;
#if __has_builtin(__builtin_amdgcn_perm)
  return __builtin_amdgcn_perm(Ya, Yb, 0x03020706u);  // {Yb.hi16, Ya.hi16}
#else
  return (Yb & 0xffff0000u) | (Ya >> 16);
#endif
}

__device__ __forceinline__ float softplus_fast(float x){
  return fmaxf(x,0.f) + __logf(1.f + __expf(-fabsf(x)));
}

__device__ __forceinline__ float softplus_f(float x){
  return fmaxf(x,0.f) + log1pf(expf(-fabsf(x)));
}

__device__ __forceinline__ short f2bf(float f){   // fp32 -> bf16 RNE
  uint32_t u = __float_as_uint(f);
  u += 0x7fffu + ((u>>16)&1u);
  return (short)(u>>16);
}

__device__ __forceinline__ float bf_round(float f){   // fp32 -> bf16 -> fp32
  uint32_t u = __float_as_uint(f);
  u += 0x7fffu + ((u>>16)&1u);
  u &= 0xffff0000u;
  return __uint_as_float(u);
}

// ---------------- K0: embeddings -> transposed bf16 hvT image (coalesced) -----------
__global__ __launch_bounds__(256) void k0_embed(
    const int* __restrict__ etype, const float* __restrict__ etime,
    const float* __restrict__ Wt,  const float* __restrict__ temb,
    const float* __restrict__ Wg,  const float* __restrict__ Wl,
    const float* __restrict__ Wn,  const float* __restrict__ Win,
    const float* __restrict__ Wpred,
    uint16_t* __restrict__ hvT, float* __restrict__ sc4,
    uint16_t* __restrict__ wbf, uint16_t* __restrict__ wd, float* __restrict__ rs){
  int blk = blockIdx.x, tid = threadIdx.x;
  if (blk < 128){
    __shared__ __align__(16) uint16_t tile[HPAD*128];   // 36864 B
    __shared__ float tvec[128];
    int b = blk >> 2, l0 = (blk & 3)*128;
    int base = b*L_ + l0;
    if (tid < 128) tvec[tid] = etime[base + tid];
    __syncthreads();
    const float M = -0.07195578414202429f;  // -ln(10000)/128
    for (int rep = 0; rep < 32; ++rep){
      int idx = rep*256 + tid;
      int k = idx >> 7, p = idx & 127;
      float dterm = __expf((float)(2*k) * M);
      float ang = (float)(l0 + p) * dterm + tvec[p] * Wt[k];
      float sv, cv;
      sincosf(ang, &sv, &cv);
      tile[k*128 + p]      = (uint16_t)f2bf(sv);
      tile[(64+k)*128 + p] = (uint16_t)f2bf(cv);
    }
    for (int rep = 0; rep < 8; ++rep){
      int idx = rep*256 + tid;
      int r = 128 + (idx >> 7), p = idx & 127;
      uint16_t v = 0;
      if (r < 132){
        int et = etype[base + p];
        v = (uint16_t)f2bf(temb[et*4 + (r-128)]);
      }
      tile[r*128 + p] = v;
    }
    if (tid < 128){
      int bl = base + tid;
      int et = etype[bl];
      float t0 = temb[et*4+0], t1 = temb[et*4+1], t2 = temb[et*4+2], t3 = temb[et*4+3];
      sc4[bl*4+0] = t0*Wg[0]+t1*Wg[1]+t2*Wg[2]+t3*Wg[3];  // dg  (j-side)
      sc4[bl*4+1] = t0*Wg[4]+t1*Wg[5]+t2*Wg[6]+t3*Wg[7];  // dg2 (i-side)
      sc4[bl*4+2] = t0*Wl[0]+t1*Wl[1]+t2*Wl[2]+t3*Wl[3];  // dl
      sc4[bl*4+3] = t0*Wl[4]+t1*Wl[5]+t2*Wl[6]+t3*Wl[7];  // dl2
    }
    __syncthreads();
    for (int pass = 0; pass < 9; ++pass){
      int r = pass*16 + (tid>>4);
      int c = tid & 15;
      ((uint4v*)(hvT + ((size_t)b*HPAD + r)*L_ + l0))[c] = ((const uint4v*)(tile + r*128))[c];
    }
  } else {
    int pb = blk - 128;                // 0..18
    if (pb < 9){                       // W_noise bf16 image (stride KSTR4) + rowsum(bf16 W)
      for (int e = tid; e < 16*KSTR4; e += 256){
        int r = e / KSTR4, k = e - r*KSTR4;
        int n = pb*16 + r;
        uint16_t v = 0;
        if (n < H_ && k < H_) v = (uint16_t)f2bf(Wn[n*H_ + k]);
        wbf[n*KSTR4 + k] = v;
      }
      if (tid < 16){
        int n = pb*16 + tid;
        if (n < H_){
          float s = 0.f;
          const float* row = Wn + (size_t)n*H_;
          #pragma unroll 4
          for (int k = 0; k < H_; ++k) s += bf_round(row[k]);
          rs[n] = s;
        }
      }
    } else {                           // [Win; Wpred] bf16 image (stride KSTR, k1 decoder)
      int rb = pb - 9;                 // 0..9
      for (int e = tid; e < 16*KSTR; e += 256){
        int r = e / KSTR, k = e - r*KSTR;
        int n = rb*16 + r;
        uint16_t v = 0;
        if (k < H_){
          if (n < H_)          v = (uint16_t)f2bf(Win[n*H_ + k]);
          else if (n < H_+NT_) v = (uint16_t)f2bf(Wpred[(n-H_)*H_ + k]);
        }
        wd[n*KSTR + k] = v;
      }
    }
  }
}

// ---------------- K1: attention flash-tile + LN + fused decoder (proven R0) ---------
// R13: phase-2 kt loop fully unrolled -> 16 independent B-loads in flight per nt.
__global__ __launch_bounds__(256) void k1_attn(
    const float* __restrict__ etime, const float* __restrict__ sc4,
    const uint16_t* __restrict__ hvT, const uint16_t* __restrict__ wd,
    const float* __restrict__ bgp, const float* __restrict__ blp,
    const float* __restrict__ gamma, const float* __restrict__ beta,
    float* __restrict__ cvec, float* __restrict__ outp){
  __shared__ __align__(16) uint16_t scb[ITILE*SCSTR];
  __shared__ float jt[L_], jg[L_], jl[L_];
  __shared__ float rt[ITILE], rg[ITILE], rl[ITILE];
  __shared__ __align__(16) float hid[ITILE*HIDS];
  __shared__ __align__(16) uint16_t hnl[ITILE*HNLS];
  __shared__ float logit[ITILE*NT_];
  __shared__ float mur[ITILE], rsr[ITILE];
  int i0 = blockIdx.x*ITILE, b = blockIdx.y, base = b*L_;
  int tid = threadIdx.x;
  float bg = bgp[0], blv = blp[0];
  for (int j = tid; j < L_; j += 256){
    jt[j] = etime[base+j];
    jg[j] = sc4[(base+j)*4+0];
    jl[j] = sc4[(base+j)*4+2];
  }
  if (tid < ITILE){
    rt[tid] = etime[base+i0+tid];
    rg[tid] = sc4[(base+i0+tid)*4+1];
    rl[tid] = sc4[(base+i0+tid)*4+3];
  }
  __syncthreads();
  // phase 1: score tile (fast transcendentals; causal zeros exact in bf16)
  for (int e = tid; e < ITILE*L_; e += 256){
    int r = e >> 9, j = e & (L_-1);
    float v = 0.f;
    if (j < i0 + r){
      float gate = __frcp_rn(1.f + __expf(-(jg[j] + rg[r] + bg)));
      float ls   = softplus_fast(jl[j] + rl[r] + blv) + 1e-6f;
      float d    = rt[r] - jt[j];
      float t2   = 2.f*ls*ls;
      v = gate * t2 * __frcp_rn(t2 + d*d);
    }
    scb[r*SCSTR + j] = (uint16_t)f2bf(v);
  }
  __syncthreads();
  // phase 2: hidden[16][H] = scores @ hv  (MFMA 16x16x32, B from hvT short8)
  int wave = tid>>6, lane = tid&63, q = lane>>4, col = lane&15;
  for (int nt = wave; nt < NTIL; nt += 4){
    int n = nt*16 + col;
    const uint16_t* bT = hvT + ((size_t)b*HPAD + n)*L_;   // 144 rows, pad rows zero
    // issue all 16 B-loads (independent), then MFMA chain
    short8 bfr[16];
    #pragma unroll
    for (int kt = 0; kt < 16; ++kt)
      bfr[kt] = *(const short8*)&bT[kt*32 + q*8];          // B[k][n]
    float4v acc = {0.f,0.f,0.f,0.f};
    #pragma unroll
    for (int kt = 0; kt < 16; ++kt){
      short8 af = *(const short8*)&scb[col*SCSTR + kt*32 + q*8];  // A[m=col][k]
      acc = __builtin_amdgcn_mfma_f32_16x16x32_bf16(af, bfr[kt], acc, 0, 0, 0);
    }
    if (n < H_){
      #pragma unroll
      for (int rr = 0; rr < 4; ++rr)
        hid[(q*4+rr)*HIDS + n] = acc[rr];    // C/D: row=q*4+rr, col=n
    }
  }
  __syncthreads();
  // LayerNorm stats
  #pragma unroll
  for (int rr = 0; rr < 4; ++rr){
    int r = wave*4 + rr;
    float x0 = hid[r*HIDS + lane];
    float x1 = hid[r*HIDS + 64 + lane];
    float x2 = (lane<4) ? hid[r*HIDS + 128 + lane] : 0.f;
    float s1 = x0+x1+x2, s2 = x0*x0+x1*x1+x2*x2;
    #pragma unroll
    for (int m=32; m; m>>=1){ s1 += __shfl_xor(s1, m, 64); s2 += __shfl_xor(s2, m, 64); }
    if (lane == 0){
      float mu = s1 * (1.f/132.f);
      float var = s2 * (1.f/132.f) - mu*mu;
      mur[r] = mu; rsr[r] = rsqrtf(var + 1e-6f);
    }
  }
  __syncthreads();
  if (tid < HNLS){
    if (tid < H_){
      float g = gamma[tid], be = beta[tid];
      #pragma unroll 4
      for (int r = 0; r < ITILE; ++r)
        hnl[r*HNLS + tid] = (uint16_t)f2bf((hid[r*HIDS+tid]-mur[r])*rsr[r]*g + be);
    } else {
      #pragma unroll 4
      for (int r = 0; r < ITILE; ++r) hnl[r*HNLS + tid] = 0;
    }
  }
  __syncthreads();
  // fused decoder: hn(16x132) @ wd(152x132)^T -> cvec + logits
  short8 afr[KCH];
  #pragma unroll
  for (int kc = 0; kc < KCH; ++kc)
    afr[kc] = *(const short8*)&hnl[col*HNLS + kc*32 + q*8];   // A[m=col][k]
  for (int nt = wave; nt < NTIL3; nt += 4){
    float4v acc = {0.f,0.f,0.f,0.f};
    const short8* bp = (const short8*)&wd[(nt*16+col)*KSTR];
    #pragma unroll
    for (int kc = 0; kc < KCH; ++kc){
      // kc=4,q>0 reads past wd row end: A zero at k>=132 -- harmless
      short8 bfr = bp[kc*4 + q];
      acc = __builtin_amdgcn_mfma_f32_16x16x32_bf16(afr[kc], bfr, acc, 0, 0, 0);
    }
    int n = nt*16 + col;
    #pragma unroll
    for (int rr = 0; rr < 4; ++rr){
      int lr = q*4 + rr;
      if (n < H_)            cvec[(size_t)(base+i0+lr)*H_ + n] = acc[rr];
      else if (n < H_+NT_)   logit[lr*NT_ + (n-H_)] = acc[rr];
    }
  }
  __syncthreads();
  if (tid < ITILE){
    float mx = -1e30f;
    #pragma unroll
    for (int j=0;j<NT_;++j) mx = fmaxf(mx, logit[tid*NT_+j]);
    float ex[NT_]; float ssum = 0.f;
    #pragma unroll
    for (int j=0;j<NT_;++j){ ex[j] = __expf(logit[tid*NT_+j]-mx); ssum += ex[j]; }
    float inv = __frcp_rn(ssum);
    #pragma unroll
    for (int j=0;j<NT_;++j)
      outp[(size_t)(B_*L_) + (size_t)(base+i0+tid)*NT_ + j] = ex[j]*inv;
  }
}

// ---------------- K4: GAN sampler (z=1, per-wave sample loop) ----------------
// R17 vs old K4: (a) grid z 7->1, wave w loops samples {w,w+8,..}: W_noise/clds
// staged once per block not 7x, atomicAdd -> direct store; (b) tail features
// 128..131 as ONE full-wave tfpair stream + shfl_xor(16) [bit-exact, verified
// R14-R16] instead of 2 streams at 16/64 active lanes; (c) W image stride
// KSTR4=140 shorts (70 dwords == 6 mod 32): ds_read_b128 conflict 8-way -> <=2-way
// (SQ_LDS_BANK_CONFLICT 9.2M -> ~1M predicted); (d) cap 85 VGPR (512,3) --
// phase-B pressure ~50, LDS 50.9KB keeps 3 blocks/CU = 24 waves.
__global__ __launch_bounds__(512, 3) void k4_sampler(
    const uint16_t* __restrict__ wbf, const float* __restrict__ cvec,
    const float* __restrict__ wt, const float* __restrict__ rs,
    float* __restrict__ outmean){
  __shared__ __align__(16) short Wlds[WBF_N4 + 16];  // +16 shorts: in-LDS slack for kc=4 tail over-read
  __shared__ __align__(16) float clds[16*CSTR];
  __shared__ float wtlds[HPAD];
  __shared__ float part[128];
  int tid = threadIdx.x, lane = tid & 63;
  int l0 = blockIdx.x*16, b = blockIdx.y;
  int bl0 = b*L_ + l0;

  {   // stage W: flat 2520 x 16B vector copy
    const uint4v* g = (const uint4v*)wbf;
    uint4v* l = (uint4v*)Wlds;
    for (int idx = tid; idx < WBF_N4/8; idx += 512) l[idx] = g[idx];
  }
  for (int m = tid>>6; m < 16; m += 8){
    for (int n = lane; n < CSTR; n += 64){
      float v = 0.f;
      if (n < H_) v = cvec[(size_t)(bl0+m)*H_ + n] - rs[n];
      clds[m*CSTR + n] = v;
    }
  }
  if (tid < HPAD) wtlds[tid] = (tid < H_) ? wt[tid] : 0.f;
  __syncthreads();

  int wave = tid >> 6;
  int q = lane >> 4, col = lane & 15;
  float msum0=0.f, msum1=0.f, msum2=0.f, msum3=0.f;
  uint32_t fb_l = (uint32_t)(bl0 + col)*(uint32_t)(SMP_*H_);
  for (int s = wave; s < SMP_; s += 8){
    uint32_t fbase = fb_l + (uint32_t)s*(uint32_t)H_;
    uint32_t fbq = fbase + (uint32_t)(q*8);
    uint4v afu[KCH];
    #pragma unroll
    for (int kc = 0; kc < 4; ++kc){
      #pragma unroll
      for (int t = 0; t < 4; ++t)
        afu[kc][t] = tfpair(fbq + (uint32_t)(kc*32 + 2*t),
                            fbq + (uint32_t)(kc*32 + 2*t + 1));
    }
    {   // tail features 128..131: one full-wave stream (q even:128/129, q odd:130/131)
      uint32_t ft = fbase + 128u + (uint32_t)((q & 1)*2);
      uint32_t w  = tfpair(ft, ft + 1u);
      uint32_t wo = (uint32_t)__shfl_xor((int)w, 16, 64);
      uint4v a4 = {0u,0u,0u,0u};
      if (q == 0){ a4[0] = w; a4[1] = wo; }
      afu[4] = a4;
    }
    float racc0=0.f, racc1=0.f, racc2=0.f, racc3=0.f;
    for (int nt = 0; nt < NTIL; ++nt){
      float4v acc = {0.f,0.f,0.f,0.f};
      const short8* bp = (const short8*)&Wlds[(nt*16+col)*KSTR4];
      #pragma unroll
      for (int kc = 0; kc < KCH; ++kc){
        short8 bfr = bp[kc*4 + q];
        acc = __builtin_amdgcn_mfma_f32_16x16x32_bf16(
                 __builtin_bit_cast(short8, afu[kc]), bfr, acc, 0, 0, 0);
      }
      int n = nt*16 + col;
      float wv = wtlds[n];
      const float* cb = &clds[(q*4)*CSTR + n];
      racc0 += fmaxf(acc[0] + cb[0*CSTR], 0.f)*wv;
      racc1 += fmaxf(acc[1] + cb[1*CSTR], 0.f)*wv;
      racc2 += fmaxf(acc[2] + cb[2*CSTR], 0.f)*wv;
      racc3 += fmaxf(acc[3] + cb[3*CSTR], 0.f)*wv;
    }
    #pragma unroll
    for (int m = 1; m < 16; m <<= 1){
      racc0 += __shfl_xor(racc0, m, 64);
      racc1 += __shfl_xor(racc1, m, 64);
      racc2 += __shfl_xor(racc2, m, 64);
      racc3 += __shfl_xor(racc3, m, 64);
    }
    msum0 += softplus_f(racc0);
    msum1 += softplus_f(racc1);
    msum2 += softplus_f(racc2);
    msum3 += softplus_f(racc3);
  }
  if (col == 0){
    part[wave*16 + q*4 + 0] = 0.02f * msum0;
    part[wave*16 + q*4 + 1] = 0.02f * msum1;
    part[wave*16 + q*4 + 2] = 0.02f * msum2;
    part[wave*16 + q*4 + 3] = 0.02f * msum3;
  }
  __syncthreads();
  if (tid < 16){
    float v = 0.f;
    #pragma unroll
    for (int w = 0; w < 8; ++w) v += part[w*16 + tid];
    outmean[bl0 + tid] = v;    // sole writer: direct store, no atomic
  }
}

// ---------------- launch ----------------
extern "C" void kernel_launch(void* const* d_in, const int* in_sizes, int n_in,
                              void* d_out, int out_size, void* d_ws, size_t ws_size,
                              hipStream_t stream){
  const int*   etype = (const int*)  d_in[0];
  const float* etime = (const float*)d_in[1];
  const float* Wt    = (const float*)d_in[3];
  const float* temb  = (const float*)d_in[4];
  const float* Wg    = (const float*)d_in[5];
  const float* bgp   = (const float*)d_in[6];
  const float* Wl    = (const float*)d_in[7];
  const float* blp   = (const float*)d_in[8];
  const float* gamma = (const float*)d_in[9];
  const float* beta  = (const float*)d_in[10];
  const float* Win   = (const float*)d_in[11];
  const float* Wn    = (const float*)d_in[12];
  const float* wtm   = (const float*)d_in[13];
  const float* Wpred = (const float*)d_in[14];
  float* out = (float*)d_out;

  uint16_t* hvT   = (uint16_t*)d_ws;                        // 32*144*512 shorts
  float*    sc4   = (float*)(hvT + (size_t)B_*HPAD*L_);     // 16384*4 floats
  float*    cvec  = sc4 + (size_t)16384*4;                  // 16384*132 floats
  float*    rs    = cvec + (size_t)16384*H_;                // 132 (+pad to 256)
  uint16_t* wbf   = (uint16_t*)(rs + 256);                  // WBF_N4 shorts
  uint16_t* wd    = wbf + (size_t)WBF_N4;                   // WDROW*KSTR shorts

  k0_embed  <<<dim3(147),   dim3(256), 0, stream>>>(etype, etime, Wt, temb, Wg, Wl,
                                                    Wn, Win, Wpred, hvT, sc4, wbf, wd, rs);
  k1_attn   <<<dim3(32,32), dim3(256), 0, stream>>>(etime, sc4, hvT, wd, bgp, blp,
                                                    gamma, beta, cvec, out);
  k4_sampler<<<dim3(32,32), dim3(512), 0, stream>>>(wbf, cvec, wtm, rs, out);
}

// Round 5
// 440.874 us; speedup vs baseline: 1.2226x; 1.2034x over previous
//
#include <hip/hip_runtime.h>
#include <stdint.h>

#define B_   32
#define L_   512
#define DT_  4
#define NT_  20
#define SMP_ 50
#define H_   132
#define HPAD 144      // padded feature rows (9 n-tiles of 16)
#define KSTR 136      // bf16 W-image k-stride (shorts) -- wd (k1 decoder)
#define KSTR4 140     // k4 W_noise image k-stride: 70 dwords == 6 mod 32 -> conflict-free (R4: 9.2M -> 0)
#define CSTR 148      // k4 clds float stride
#define KCH  5        // 5 k-chunks of 32 (K padded 132 -> 160)
#define NTIL 9
#define WBF_N4 (HPAD*KSTR4)    // 20160 shorts (40320 B)
#define ITILE 16      // k1 i-rows per block
#define SCSTR 520     // k1 score-row stride (shorts)
#define HIDS  136     // k1 hid row stride (floats)
#define HNLS  160     // k1 fused-decoder hn LDS row stride (shorts)
#define WDROW 160     // [Win;Wpred] image rows (152 used)
#define NTIL3 10      // decoder n-tiles

typedef float  float4v __attribute__((ext_vector_type(4)));
typedef short  short8  __attribute__((ext_vector_type(8)));
typedef unsigned int uint4v __attribute__((ext_vector_type(4)));

#if __has_builtin(__builtin_rotateleft32)
#define ROTL(x,r) __builtin_rotateleft32((x),(r))
#elif __has_builtin(__builtin_amdgcn_alignbit)
#define ROTL(x,r) __builtin_amdgcn_alignbit((x),(x),32u-(r))
#else
#define ROTL(x,r) (((x)<<(r))|((x)>>(32u-(r))))
#endif

// ---------------- threefry2x32, key=(0,42), JAX partitionable 32-bit path ------------
// bits[f] = o0 ^ o1 of threefry2x32((0,42), ctr=(0,f))  [verified R5-R12]
__device__ __forceinline__ uint32_t tfpair(uint32_t fa, uint32_t fb){
  const uint32_t ks1 = 42u;
  const uint32_t ks2 = 0x1BD11BDAu ^ 42u;
  uint32_t a0 = 0u, b0 = 0u, a1 = fa + ks1, b1 = fb + ks1;
#define TFR(r) a0+=a1; b0+=b1; a1=ROTL(a1,(r)); b1=ROTL(b1,(r)); a1^=a0; b1^=b0;
  TFR(13) TFR(15) TFR(26) TFR(6)
  a0+=ks1; a1+=ks2+1u; b0+=ks1; b1+=ks2+1u;
  TFR(17) TFR(29) TFR(16) TFR(24)
  a0+=ks2; a1+=2u;     b0+=ks2; b1+=2u;       // ks0+2
  TFR(13) TFR(15) TFR(26) TFR(6)
  a1+=ks1+3u;          b1+=ks1+3u;            // x0+=ks0 (0)
  TFR(17) TFR(29) TFR(16) TFR(24)
  a0+=ks1; a1+=ks2+4u; b0+=ks1; b1+=ks2+4u;
  TFR(13) TFR(15) TFR(26) TFR(6)
  a0+=ks2; a1+=5u;     b0+=ks2; b1+=5u;       // ks0+5
#undef TFR
  uint32_t Ya = ((a0 ^ a1) >> 9) + 0x3f808000u;   // bf16 bits in [31:16], RHU rounding
  uint32_t Yb = ((b0 ^ b1) >> 9) + 0x3f808000u;
#if __has_builtin(__builtin_amdgcn_perm)
  return __builtin_amdgcn_perm(Ya, Yb, 0x03020706u);  // {Yb.hi16, Ya.hi16}
#else
  return (Yb & 0xffff0000u) | (Ya >> 16);
#endif
}

__device__ __forceinline__ float softplus_fast(float x){
  return fmaxf(x,0.f) + __logf(1.f + __expf(-fabsf(x)));
}

__device__ __forceinline__ float softplus_f(float x){
  return fmaxf(x,0.f) + log1pf(expf(-fabsf(x)));
}

__device__ __forceinline__ short f2bf(float f){   // fp32 -> bf16 RNE
  uint32_t u = __float_as_uint(f);
  u += 0x7fffu + ((u>>16)&1u);
  return (short)(u>>16);
}

__device__ __forceinline__ float bf_round(float f){   // fp32 -> bf16 -> fp32
  uint32_t u = __float_as_uint(f);
  u += 0x7fffu + ((u>>16)&1u);
  u &= 0xffff0000u;
  return __uint_as_float(u);
}

// ---------------- K0: embeddings -> transposed bf16 hvT image (coalesced) -----------
__global__ __launch_bounds__(256) void k0_embed(
    const int* __restrict__ etype, const float* __restrict__ etime,
    const float* __restrict__ Wt,  const float* __restrict__ temb,
    const float* __restrict__ Wg,  const float* __restrict__ Wl,
    const float* __restrict__ Wn,  const float* __restrict__ Win,
    const float* __restrict__ Wpred,
    uint16_t* __restrict__ hvT, float* __restrict__ sc4, float* __restrict__ outmean,
    uint16_t* __restrict__ wbf, uint16_t* __restrict__ wd, float* __restrict__ rs){
  int blk = blockIdx.x, tid = threadIdx.x;
  if (blk < 128){
    __shared__ __align__(16) uint16_t tile[HPAD*128];   // 36864 B
    __shared__ float tvec[128];
    int b = blk >> 2, l0 = (blk & 3)*128;
    int base = b*L_ + l0;
    if (tid < 128) tvec[tid] = etime[base + tid];
    __syncthreads();
    const float M = -0.07195578414202429f;  // -ln(10000)/128
    for (int rep = 0; rep < 32; ++rep){
      int idx = rep*256 + tid;
      int k = idx >> 7, p = idx & 127;
      float dterm = __expf((float)(2*k) * M);
      float ang = (float)(l0 + p) * dterm + tvec[p] * Wt[k];
      float sv, cv;
      sincosf(ang, &sv, &cv);
      tile[k*128 + p]      = (uint16_t)f2bf(sv);
      tile[(64+k)*128 + p] = (uint16_t)f2bf(cv);
    }
    for (int rep = 0; rep < 8; ++rep){
      int idx = rep*256 + tid;
      int r = 128 + (idx >> 7), p = idx & 127;
      uint16_t v = 0;
      if (r < 132){
        int et = etype[base + p];
        v = (uint16_t)f2bf(temb[et*4 + (r-128)]);
      }
      tile[r*128 + p] = v;
    }
    if (tid < 128){
      int bl = base + tid;
      int et = etype[bl];
      float t0 = temb[et*4+0], t1 = temb[et*4+1], t2 = temb[et*4+2], t3 = temb[et*4+3];
      sc4[bl*4+0] = t0*Wg[0]+t1*Wg[1]+t2*Wg[2]+t3*Wg[3];  // dg  (j-side)
      sc4[bl*4+1] = t0*Wg[4]+t1*Wg[5]+t2*Wg[6]+t3*Wg[7];  // dg2 (i-side)
      sc4[bl*4+2] = t0*Wl[0]+t1*Wl[1]+t2*Wl[2]+t3*Wl[3];  // dl
      sc4[bl*4+3] = t0*Wl[4]+t1*Wl[5]+t2*Wl[6]+t3*Wl[7];  // dl2
      outmean[bl] = 0.f;                                   // zero for k4 atomics
    }
    __syncthreads();
    for (int pass = 0; pass < 9; ++pass){
      int r = pass*16 + (tid>>4);
      int c = tid & 15;
      ((uint4v*)(hvT + ((size_t)b*HPAD + r)*L_ + l0))[c] = ((const uint4v*)(tile + r*128))[c];
    }
  } else {
    int pb = blk - 128;                // 0..18
    if (pb < 9){                       // W_noise bf16 image (stride KSTR4) + rowsum(bf16 W)
      for (int e = tid; e < 16*KSTR4; e += 256){
        int r = e / KSTR4, k = e - r*KSTR4;
        int n = pb*16 + r;
        uint16_t v = 0;
        if (n < H_ && k < H_) v = (uint16_t)f2bf(Wn[n*H_ + k]);
        wbf[n*KSTR4 + k] = v;
      }
      if (tid < 16){
        int n = pb*16 + tid;
        if (n < H_){
          float s = 0.f;
          const float* row = Wn + (size_t)n*H_;
          #pragma unroll 4
          for (int k = 0; k < H_; ++k) s += bf_round(row[k]);
          rs[n] = s;
        }
      }
    } else {                           // [Win; Wpred] bf16 image (stride KSTR, k1 decoder)
      int rb = pb - 9;                 // 0..9
      for (int e = tid; e < 16*KSTR; e += 256){
        int r = e / KSTR, k = e - r*KSTR;
        int n = rb*16 + r;
        uint16_t v = 0;
        if (k < H_){
          if (n < H_)          v = (uint16_t)f2bf(Win[n*H_ + k]);
          else if (n < H_+NT_) v = (uint16_t)f2bf(Wpred[(n-H_)*H_ + k]);
        }
        wd[n*KSTR + k] = v;
      }
    }
  }
}

// ---------------- K1: attention flash-tile + LN + fused decoder (proven R0) ---------
// R13: phase-2 kt loop fully unrolled -> 16 independent B-loads in flight per nt.
__global__ __launch_bounds__(256) void k1_attn(
    const float* __restrict__ etime, const float* __restrict__ sc4,
    const uint16_t* __restrict__ hvT, const uint16_t* __restrict__ wd,
    const float* __restrict__ bgp, const float* __restrict__ blp,
    const float* __restrict__ gamma, const float* __restrict__ beta,
    float* __restrict__ cvec, float* __restrict__ outp){
  __shared__ __align__(16) uint16_t scb[ITILE*SCSTR];
  __shared__ float jt[L_], jg[L_], jl[L_];
  __shared__ float rt[ITILE], rg[ITILE], rl[ITILE];
  __shared__ __align__(16) float hid[ITILE*HIDS];
  __shared__ __align__(16) uint16_t hnl[ITILE*HNLS];
  __shared__ float logit[ITILE*NT_];
  __shared__ float mur[ITILE], rsr[ITILE];
  int i0 = blockIdx.x*ITILE, b = blockIdx.y, base = b*L_;
  int tid = threadIdx.x;
  float bg = bgp[0], blv = blp[0];
  for (int j = tid; j < L_; j += 256){
    jt[j] = etime[base+j];
    jg[j] = sc4[(base+j)*4+0];
    jl[j] = sc4[(base+j)*4+2];
  }
  if (tid < ITILE){
    rt[tid] = etime[base+i0+tid];
    rg[tid] = sc4[(base+i0+tid)*4+1];
    rl[tid] = sc4[(base+i0+tid)*4+3];
  }
  __syncthreads();
  // phase 1: score tile (fast transcendentals; causal zeros exact in bf16)
  for (int e = tid; e < ITILE*L_; e += 256){
    int r = e >> 9, j = e & (L_-1);
    float v = 0.f;
    if (j < i0 + r){
      float gate = __frcp_rn(1.f + __expf(-(jg[j] + rg[r] + bg)));
      float ls   = softplus_fast(jl[j] + rl[r] + blv) + 1e-6f;
      float d    = rt[r] - jt[j];
      float t2   = 2.f*ls*ls;
      v = gate * t2 * __frcp_rn(t2 + d*d);
    }
    scb[r*SCSTR + j] = (uint16_t)f2bf(v);
  }
  __syncthreads();
  // phase 2: hidden[16][H] = scores @ hv  (MFMA 16x16x32, B from hvT short8)
  int wave = tid>>6, lane = tid&63, q = lane>>4, col = lane&15;
  for (int nt = wave; nt < NTIL; nt += 4){
    int n = nt*16 + col;
    const uint16_t* bT = hvT + ((size_t)b*HPAD + n)*L_;   // 144 rows, pad rows zero
    // issue all 16 B-loads (independent), then MFMA chain
    short8 bfr[16];
    #pragma unroll
    for (int kt = 0; kt < 16; ++kt)
      bfr[kt] = *(const short8*)&bT[kt*32 + q*8];          // B[k][n]
    float4v acc = {0.f,0.f,0.f,0.f};
    #pragma unroll
    for (int kt = 0; kt < 16; ++kt){
      short8 af = *(const short8*)&scb[col*SCSTR + kt*32 + q*8];  // A[m=col][k]
      acc = __builtin_amdgcn_mfma_f32_16x16x32_bf16(af, bfr[kt], acc, 0, 0, 0);
    }
    if (n < H_){
      #pragma unroll
      for (int rr = 0; rr < 4; ++rr)
        hid[(q*4+rr)*HIDS + n] = acc[rr];    // C/D: row=q*4+rr, col=n
    }
  }
  __syncthreads();
  // LayerNorm stats
  #pragma unroll
  for (int rr = 0; rr < 4; ++rr){
    int r = wave*4 + rr;
    float x0 = hid[r*HIDS + lane];
    float x1 = hid[r*HIDS + 64 + lane];
    float x2 = (lane<4) ? hid[r*HIDS + 128 + lane] : 0.f;
    float s1 = x0+x1+x2, s2 = x0*x0+x1*x1+x2*x2;
    #pragma unroll
    for (int m=32; m; m>>=1){ s1 += __shfl_xor(s1, m, 64); s2 += __shfl_xor(s2, m, 64); }
    if (lane == 0){
      float mu = s1 * (1.f/132.f);
      float var = s2 * (1.f/132.f) - mu*mu;
      mur[r] = mu; rsr[r] = rsqrtf(var + 1e-6f);
    }
  }
  __syncthreads();
  if (tid < HNLS){
    if (tid < H_){
      float g = gamma[tid], be = beta[tid];
      #pragma unroll 4
      for (int r = 0; r < ITILE; ++r)
        hnl[r*HNLS + tid] = (uint16_t)f2bf((hid[r*HIDS+tid]-mur[r])*rsr[r]*g + be);
    } else {
      #pragma unroll 4
      for (int r = 0; r < ITILE; ++r) hnl[r*HNLS + tid] = 0;
    }
  }
  __syncthreads();
  // fused decoder: hn(16x132) @ wd(152x132)^T -> cvec + logits
  short8 afr[KCH];
  #pragma unroll
  for (int kc = 0; kc < KCH; ++kc)
    afr[kc] = *(const short8*)&hnl[col*HNLS + kc*32 + q*8];   // A[m=col][k]
  for (int nt = wave; nt < NTIL3; nt += 4){
    float4v acc = {0.f,0.f,0.f,0.f};
    const short8* bp = (const short8*)&wd[(nt*16+col)*KSTR];
    #pragma unroll
    for (int kc = 0; kc < KCH; ++kc){
      // kc=4,q>0 reads past wd row end: A zero at k>=132 -- harmless
      short8 bfr = bp[kc*4 + q];
      acc = __builtin_amdgcn_mfma_f32_16x16x32_bf16(afr[kc], bfr, acc, 0, 0, 0);
    }
    int n = nt*16 + col;
    #pragma unroll
    for (int rr = 0; rr < 4; ++rr){
      int lr = q*4 + rr;
      if (n < H_)            cvec[(size_t)(base+i0+lr)*H_ + n] = acc[rr];
      else if (n < H_+NT_)   logit[lr*NT_ + (n-H_)] = acc[rr];
    }
  }
  __syncthreads();
  if (tid < ITILE){
    float mx = -1e30f;
    #pragma unroll
    for (int j=0;j<NT_;++j) mx = fmaxf(mx, logit[tid*NT_+j]);
    float ex[NT_]; float ssum = 0.f;
    #pragma unroll
    for (int j=0;j<NT_;++j){ ex[j] = __expf(logit[tid*NT_+j]-mx); ssum += ex[j]; }
    float inv = __frcp_rn(ssum);
    #pragma unroll
    for (int j=0;j<NT_;++j)
      outp[(size_t)(B_*L_) + (size_t)(base+i0+tid)*NT_ + j] = ex[j]*inv;
  }
}

// ---------------- K4: GAN sampler (R0 loop-free structure + verified fixes) ---------
// R18: the R4 sample-loop version spilled at any cap (compiler pipelines next
// sample's tfpairs across the MFMA section: 950MB scratch, VALUBusy 56%).
// Revert to R0's z=7 one-sample-per-wave shape (proven 40 VGPR, 0 spill,
// 92.7% VALUBusy) keeping only the two verified wins:
//   (a) KSTR4=140 W-image stride -> SQ_LDS_BANK_CONFLICT 9.2M -> 0 (R4-verified)
//   (b) tail features 128..131 as ONE full-wave tfpair stream + shfl_xor(16)
//       (bit-exact R1-R4) instead of 2 streams at 16/64 active lanes.
__global__ __launch_bounds__(512, 6) void k4_sampler(
    const uint16_t* __restrict__ wbf, const float* __restrict__ cvec,
    const float* __restrict__ wt, const float* __restrict__ rs,
    float* __restrict__ outmean){
  __shared__ __align__(16) short Wlds[WBF_N4 + 32];  // +32: slack for kc=4 tail over-read
  __shared__ __align__(16) float clds[16*CSTR];
  __shared__ float wtlds[HPAD];
  __shared__ float part[128];
  int tid = threadIdx.x, lane = tid & 63;
  int l0 = blockIdx.x*16, b = blockIdx.y, sch = blockIdx.z;
  int bl0 = b*L_ + l0;

  {   // stage W: flat 2520 x 16B vector copy
    const uint4v* g = (const uint4v*)wbf;
    uint4v* l = (uint4v*)Wlds;
    for (int idx = tid; idx < WBF_N4/8; idx += 512) l[idx] = g[idx];
  }
  for (int m = tid>>6; m < 16; m += 8){
    for (int n = lane; n < CSTR; n += 64){
      float v = 0.f;
      if (n < H_) v = cvec[(size_t)(bl0+m)*H_ + n] - rs[n];
      clds[m*CSTR + n] = v;
    }
  }
  if (tid < HPAD) wtlds[tid] = (tid < H_) ? wt[tid] : 0.f;
  if (tid < 128) part[tid] = 0.f;
  __syncthreads();

  int wave = tid >> 6;
  int q = lane >> 4, col = lane & 15;
  int s = sch*8 + wave;
  if (s < SMP_){
    uint32_t fbase = (uint32_t)(bl0 + col)*(uint32_t)(SMP_*H_)
                   + (uint32_t)s*(uint32_t)H_;
    uint32_t fbq = fbase + (uint32_t)(q*8);
    uint4v afu[KCH];
    #pragma unroll
    for (int kc = 0; kc < 4; ++kc){
      #pragma unroll
      for (int t = 0; t < 4; ++t)
        afu[kc][t] = tfpair(fbq + (uint32_t)(kc*32 + 2*t),
                            fbq + (uint32_t)(kc*32 + 2*t + 1));
    }
    {   // tail features 128..131: one full-wave stream (q even:128/129, q odd:130/131)
      uint32_t ft = fbase + 128u + (uint32_t)((q & 1)*2);
      uint32_t w  = tfpair(ft, ft + 1u);
      uint32_t wo = (uint32_t)__shfl_xor((int)w, 16, 64);
      uint4v a4 = {0u,0u,0u,0u};
      if (q == 0){ a4[0] = w; a4[1] = wo; }
      afu[4] = a4;
    }
    float racc0=0.f, racc1=0.f, racc2=0.f, racc3=0.f;
    for (int nt = 0; nt < NTIL; ++nt){
      float4v acc = {0.f,0.f,0.f,0.f};
      const short8* bp = (const short8*)&Wlds[(nt*16+col)*KSTR4];
      #pragma unroll
      for (int kc = 0; kc < KCH; ++kc){
        short8 bfr = bp[kc*4 + q];
        acc = __builtin_amdgcn_mfma_f32_16x16x32_bf16(
                 __builtin_bit_cast(short8, afu[kc]), bfr, acc, 0, 0, 0);
      }
      int n = nt*16 + col;
      float wv = wtlds[n];
      const float* cb = &clds[(q*4)*CSTR + n];
      racc0 += fmaxf(acc[0] + cb[0*CSTR], 0.f)*wv;
      racc1 += fmaxf(acc[1] + cb[1*CSTR], 0.f)*wv;
      racc2 += fmaxf(acc[2] + cb[2*CSTR], 0.f)*wv;
      racc3 += fmaxf(acc[3] + cb[3*CSTR], 0.f)*wv;
    }
    #pragma unroll
    for (int m = 1; m < 16; m <<= 1){
      racc0 += __shfl_xor(racc0, m, 64);
      racc1 += __shfl_xor(racc1, m, 64);
      racc2 += __shfl_xor(racc2, m, 64);
      racc3 += __shfl_xor(racc3, m, 64);
    }
    if (col == 0){
      part[wave*16 + q*4 + 0] = 0.02f * softplus_f(racc0);
      part[wave*16 + q*4 + 1] = 0.02f * softplus_f(racc1);
      part[wave*16 + q*4 + 2] = 0.02f * softplus_f(racc2);
      part[wave*16 + q*4 + 3] = 0.02f * softplus_f(racc3);
    }
  }
  __syncthreads();
  if (tid < 16){
    float v = 0.f;
    #pragma unroll
    for (int w = 0; w < 8; ++w) v += part[w*16 + tid];
    atomicAdd(&outmean[bl0 + tid], v);
  }
}

// ---------------- launch ----------------
extern "C" void kernel_launch(void* const* d_in, const int* in_sizes, int n_in,
                              void* d_out, int out_size, void* d_ws, size_t ws_size,
                              hipStream_t stream){
  const int*   etype = (const int*)  d_in[0];
  const float* etime = (const float*)d_in[1];
  const float* Wt    = (const float*)d_in[3];
  const float* temb  = (const float*)d_in[4];
  const float* Wg    = (const float*)d_in[5];
  const float* bgp   = (const float*)d_in[6];
  const float* Wl    = (const float*)d_in[7];
  const float* blp   = (const float*)d_in[8];
  const float* gamma = (const float*)d_in[9];
  const float* beta  = (const float*)d_in[10];
  const float* Win   = (const float*)d_in[11];
  const float* Wn    = (const float*)d_in[12];
  const float* wtm   = (const float*)d_in[13];
  const float* Wpred = (const float*)d_in[14];
  float* out = (float*)d_out;

  uint16_t* hvT   = (uint16_t*)d_ws;                        // 32*144*512 shorts
  float*    sc4   = (float*)(hvT + (size_t)B_*HPAD*L_);     // 16384*4 floats
  float*    cvec  = sc4 + (size_t)16384*4;                  // 16384*132 floats
  float*    rs    = cvec + (size_t)16384*H_;                // 132 (+pad to 256)
  uint16_t* wbf   = (uint16_t*)(rs + 256);                  // WBF_N4 shorts
  uint16_t* wd    = wbf + (size_t)WBF_N4;                   // WDROW*KSTR shorts

  k0_embed  <<<dim3(147),     dim3(256), 0, stream>>>(etype, etime, Wt, temb, Wg, Wl,
                                                      Wn, Win, Wpred, hvT, sc4, out, wbf, wd, rs);
  k1_attn   <<<dim3(32,32),   dim3(256), 0, stream>>>(etime, sc4, hvT, wd, bgp, blp,
                                                      gamma, beta, cvec, out);
  k4_sampler<<<dim3(32,32,7), dim3(512), 0, stream>>>(wbf, cvec, wtm, rs, out);
}

// Round 6
// 381.604 us; speedup vs baseline: 1.4125x; 1.1553x over previous
//
#include <hip/hip_runtime.h>
#include <stdint.h>

#define B_   32
#define L_   512
#define DT_  4
#define NT_  20
#define SMP_ 50
#define H_   132
#define HPAD 144      // padded feature rows (9 n-tiles of 16)
#define KSTR 136      // bf16 W-image k-stride (shorts), 272B = 17x16B -> ds_read_b128 aligned
#define CSTR 148      // k4 clds float stride
#define KCH  5        // 5 k-chunks of 32 (K padded 132 -> 160)
#define NTIL 9
#define WBF_N (HPAD*KSTR)      // 19584 shorts
#define ITILE 16      // k1 i-rows per block
#define SCSTR 520     // k1 score-row stride (shorts)
#define HIDS  136     // k1 hid row stride (floats)
#define HNLS  160     // k1 fused-decoder hn LDS row stride (shorts)
#define WDROW 160     // [Win;Wpred] image rows (152 used)
#define NTIL3 10      // decoder n-tiles

typedef float  float4v __attribute__((ext_vector_type(4)));
typedef short  short8  __attribute__((ext_vector_type(8)));
typedef unsigned int uint4v __attribute__((ext_vector_type(4)));

#if __has_builtin(__builtin_rotateleft32)
#define ROTL(x,r) __builtin_rotateleft32((x),(r))
#elif __has_builtin(__builtin_amdgcn_alignbit)
#define ROTL(x,r) __builtin_amdgcn_alignbit((x),(x),32u-(r))
#else
#define ROTL(x,r) (((x)<<(r))|((x)>>(32u-(r))))
#endif

// ---------------- threefry2x32, key=(0,42), JAX partitionable 32-bit path ------------
// bits[f] = o0 ^ o1 of threefry2x32((0,42), ctr=(0,f))  [verified R5-R12]
__device__ __forceinline__ uint32_t tfpair(uint32_t fa, uint32_t fb){
  const uint32_t ks1 = 42u;
  const uint32_t ks2 = 0x1BD11BDAu ^ 42u;
  uint32_t a0 = 0u, b0 = 0u, a1 = fa + ks1, b1 = fb + ks1;
#define TFR(r) a0+=a1; b0+=b1; a1=ROTL(a1,(r)); b1=ROTL(b1,(r)); a1^=a0; b1^=b0;
  TFR(13) TFR(15) TFR(26) TFR(6)
  a0+=ks1; a1+=ks2+1u; b0+=ks1; b1+=ks2+1u;
  TFR(17) TFR(29) TFR(16) TFR(24)
  a0+=ks2; a1+=2u;     b0+=ks2; b1+=2u;       // ks0+2
  TFR(13) TFR(15) TFR(26) TFR(6)
  a1+=ks1+3u;          b1+=ks1+3u;            // x0+=ks0 (0)
  TFR(17) TFR(29) TFR(16) TFR(24)
  a0+=ks1; a1+=ks2+4u; b0+=ks1; b1+=ks2+4u;
  TFR(13) TFR(15) TFR(26) TFR(6)
  a0+=ks2; a1+=5u;     b0+=ks2; b1+=5u;       // ks0+5
#undef TFR
  uint32_t Ya = ((a0 ^ a1) >> 9) + 0x3f808000u;   // bf16 bits in [31:16], RHU rounding
  uint32_t Yb = ((b0 ^ b1) >> 9) + 0x3f808000u;
#if __has_builtin(__builtin_amdgcn_perm)
  return __builtin_amdgcn_perm(Ya, Yb, 0x03020706u);  // {Yb.hi16, Ya.hi16}
#else
  return (Yb & 0xffff0000u) | (Ya >> 16);
#endif
}

__device__ __forceinline__ float softplus_fast(float x){
  return fmaxf(x,0.f) + __logf(1.f + __expf(-fabsf(x)));
}

__device__ __forceinline__ float softplus_f(float x){
  return fmaxf(x,0.f) + log1pf(expf(-fabsf(x)));
}

__device__ __forceinline__ short f2bf(float f){   // fp32 -> bf16 RNE
  uint32_t u = __float_as_uint(f);
  u += 0x7fffu + ((u>>16)&1u);
  return (short)(u>>16);
}

__device__ __forceinline__ float bf_round(float f){   // fp32 -> bf16 -> fp32
  uint32_t u = __float_as_uint(f);
  u += 0x7fffu + ((u>>16)&1u);
  u &= 0xffff0000u;
  return __uint_as_float(u);
}

// ---------------- K0: embeddings -> transposed bf16 hvT image (coalesced) -----------
__global__ __launch_bounds__(256) void k0_embed(
    const int* __restrict__ etype, const float* __restrict__ etime,
    const float* __restrict__ Wt,  const float* __restrict__ temb,
    const float* __restrict__ Wg,  const float* __restrict__ Wl,
    const float* __restrict__ Wn,  const float* __restrict__ Win,
    const float* __restrict__ Wpred,
    uint16_t* __restrict__ hvT, float* __restrict__ sc4, float* __restrict__ outmean,
    uint16_t* __restrict__ wbf, uint16_t* __restrict__ wd, float* __restrict__ rs){
  int blk = blockIdx.x, tid = threadIdx.x;
  if (blk < 128){
    __shared__ __align__(16) uint16_t tile[HPAD*128];   // 36864 B
    __shared__ float tvec[128];
    int b = blk >> 2, l0 = (blk & 3)*128;
    int base = b*L_ + l0;
    if (tid < 128) tvec[tid] = etime[base + tid];
    __syncthreads();
    const float M = -0.07195578414202429f;  // -ln(10000)/128
    for (int rep = 0; rep < 32; ++rep){
      int idx = rep*256 + tid;
      int k = idx >> 7, p = idx & 127;
      float dterm = __expf((float)(2*k) * M);
      float ang = (float)(l0 + p) * dterm + tvec[p] * Wt[k];
      float sv, cv;
      sincosf(ang, &sv, &cv);
      tile[k*128 + p]      = (uint16_t)f2bf(sv);
      tile[(64+k)*128 + p] = (uint16_t)f2bf(cv);
    }
    for (int rep = 0; rep < 8; ++rep){
      int idx = rep*256 + tid;
      int r = 128 + (idx >> 7), p = idx & 127;
      uint16_t v = 0;
      if (r < 132){
        int et = etype[base + p];
        v = (uint16_t)f2bf(temb[et*4 + (r-128)]);
      }
      tile[r*128 + p] = v;
    }
    if (tid < 128){
      int bl = base + tid;
      int et = etype[bl];
      float t0 = temb[et*4+0], t1 = temb[et*4+1], t2 = temb[et*4+2], t3 = temb[et*4+3];
      sc4[bl*4+0] = t0*Wg[0]+t1*Wg[1]+t2*Wg[2]+t3*Wg[3];  // dg  (j-side)
      sc4[bl*4+1] = t0*Wg[4]+t1*Wg[5]+t2*Wg[6]+t3*Wg[7];  // dg2 (i-side)
      sc4[bl*4+2] = t0*Wl[0]+t1*Wl[1]+t2*Wl[2]+t3*Wl[3];  // dl
      sc4[bl*4+3] = t0*Wl[4]+t1*Wl[5]+t2*Wl[6]+t3*Wl[7];  // dl2
      outmean[bl] = 0.f;                                   // zero for k4 atomics
    }
    __syncthreads();
    for (int pass = 0; pass < 9; ++pass){
      int r = pass*16 + (tid>>4);
      int c = tid & 15;
      ((uint4v*)(hvT + ((size_t)b*HPAD + r)*L_ + l0))[c] = ((const uint4v*)(tile + r*128))[c];
    }
  } else {
    int pb = blk - 128;                // 0..18
    if (pb < 9){                       // W_noise bf16 image + rowsum(bf16 W)
      for (int e = tid; e < 16*KSTR; e += 256){
        int r = e / KSTR, k = e - r*KSTR;
        int n = pb*16 + r;
        uint16_t v = 0;
        if (n < H_ && k < H_) v = (uint16_t)f2bf(Wn[n*H_ + k]);
        wbf[n*KSTR + k] = v;
      }
      if (tid < 16){
        int n = pb*16 + tid;
        if (n < H_){
          float s = 0.f;
          const float* row = Wn + (size_t)n*H_;
          #pragma unroll 4
          for (int k = 0; k < H_; ++k) s += bf_round(row[k]);
          rs[n] = s;
        }
      }
    } else {                           // [Win; Wpred] bf16 image
      int rb = pb - 9;                 // 0..9
      for (int e = tid; e < 16*KSTR; e += 256){
        int r = e / KSTR, k = e - r*KSTR;
        int n = rb*16 + r;
        uint16_t v = 0;
        if (k < H_){
          if (n < H_)          v = (uint16_t)f2bf(Win[n*H_ + k]);
          else if (n < H_+NT_) v = (uint16_t)f2bf(Wpred[(n-H_)*H_ + k]);
        }
        wd[n*KSTR + k] = v;
      }
    }
  }
}

// ---------------- K1: attention flash-tile + LN + fused decoder (proven R0) ---------
// R13: phase-2 kt loop fully unrolled -> 16 independent B-loads in flight per nt.
__global__ __launch_bounds__(256) void k1_attn(
    const float* __restrict__ etime, const float* __restrict__ sc4,
    const uint16_t* __restrict__ hvT, const uint16_t* __restrict__ wd,
    const float* __restrict__ bgp, const float* __restrict__ blp,
    const float* __restrict__ gamma, const float* __restrict__ beta,
    float* __restrict__ cvec, float* __restrict__ outp){
  __shared__ __align__(16) uint16_t scb[ITILE*SCSTR];
  __shared__ float jt[L_], jg[L_], jl[L_];
  __shared__ float rt[ITILE], rg[ITILE], rl[ITILE];
  __shared__ __align__(16) float hid[ITILE*HIDS];
  __shared__ __align__(16) uint16_t hnl[ITILE*HNLS];
  __shared__ float logit[ITILE*NT_];
  __shared__ float mur[ITILE], rsr[ITILE];
  int i0 = blockIdx.x*ITILE, b = blockIdx.y, base = b*L_;
  int tid = threadIdx.x;
  float bg = bgp[0], blv = blp[0];
  for (int j = tid; j < L_; j += 256){
    jt[j] = etime[base+j];
    jg[j] = sc4[(base+j)*4+0];
    jl[j] = sc4[(base+j)*4+2];
  }
  if (tid < ITILE){
    rt[tid] = etime[base+i0+tid];
    rg[tid] = sc4[(base+i0+tid)*4+1];
    rl[tid] = sc4[(base+i0+tid)*4+3];
  }
  __syncthreads();
  // phase 1: score tile (fast transcendentals; causal zeros exact in bf16)
  for (int e = tid; e < ITILE*L_; e += 256){
    int r = e >> 9, j = e & (L_-1);
    float v = 0.f;
    if (j < i0 + r){
      float gate = __frcp_rn(1.f + __expf(-(jg[j] + rg[r] + bg)));
      float ls   = softplus_fast(jl[j] + rl[r] + blv) + 1e-6f;
      float d    = rt[r] - jt[j];
      float t2   = 2.f*ls*ls;
      v = gate * t2 * __frcp_rn(t2 + d*d);
    }
    scb[r*SCSTR + j] = (uint16_t)f2bf(v);
  }
  __syncthreads();
  // phase 2: hidden[16][H] = scores @ hv  (MFMA 16x16x32, B from hvT short8)
  int wave = tid>>6, lane = tid&63, q = lane>>4, col = lane&15;
  for (int nt = wave; nt < NTIL; nt += 4){
    int n = nt*16 + col;
    const uint16_t* bT = hvT + ((size_t)b*HPAD + n)*L_;   // 144 rows, pad rows zero
    // issue all 16 B-loads (independent), then MFMA chain
    short8 bfr[16];
    #pragma unroll
    for (int kt = 0; kt < 16; ++kt)
      bfr[kt] = *(const short8*)&bT[kt*32 + q*8];          // B[k][n]
    float4v acc = {0.f,0.f,0.f,0.f};
    #pragma unroll
    for (int kt = 0; kt < 16; ++kt){
      short8 af = *(const short8*)&scb[col*SCSTR + kt*32 + q*8];  // A[m=col][k]
      acc = __builtin_amdgcn_mfma_f32_16x16x32_bf16(af, bfr[kt], acc, 0, 0, 0);
    }
    if (n < H_){
      #pragma unroll
      for (int rr = 0; rr < 4; ++rr)
        hid[(q*4+rr)*HIDS + n] = acc[rr];    // C/D: row=q*4+rr, col=n
    }
  }
  __syncthreads();
  // LayerNorm stats
  #pragma unroll
  for (int rr = 0; rr < 4; ++rr){
    int r = wave*4 + rr;
    float x0 = hid[r*HIDS + lane];
    float x1 = hid[r*HIDS + 64 + lane];
    float x2 = (lane<4) ? hid[r*HIDS + 128 + lane] : 0.f;
    float s1 = x0+x1+x2, s2 = x0*x0+x1*x1+x2*x2;
    #pragma unroll
    for (int m=32; m; m>>=1){ s1 += __shfl_xor(s1, m, 64); s2 += __shfl_xor(s2, m, 64); }
    if (lane == 0){
      float mu = s1 * (1.f/132.f);
      float var = s2 * (1.f/132.f) - mu*mu;
      mur[r] = mu; rsr[r] = rsqrtf(var + 1e-6f);
    }
  }
  __syncthreads();
  if (tid < HNLS){
    if (tid < H_){
      float g = gamma[tid], be = beta[tid];
      #pragma unroll 4
      for (int r = 0; r < ITILE; ++r)
        hnl[r*HNLS + tid] = (uint16_t)f2bf((hid[r*HIDS+tid]-mur[r])*rsr[r]*g + be);
    } else {
      #pragma unroll 4
      for (int r = 0; r < ITILE; ++r) hnl[r*HNLS + tid] = 0;
    }
  }
  __syncthreads();
  // fused decoder: hn(16x132) @ wd(152x132)^T -> cvec + logits
  short8 afr[KCH];
  #pragma unroll
  for (int kc = 0; kc < KCH; ++kc)
    afr[kc] = *(const short8*)&hnl[col*HNLS + kc*32 + q*8];   // A[m=col][k]
  for (int nt = wave; nt < NTIL3; nt += 4){
    float4v acc = {0.f,0.f,0.f,0.f};
    const short8* bp = (const short8*)&wd[(nt*16+col)*KSTR];
    #pragma unroll
    for (int kc = 0; kc < KCH; ++kc){
      // kc=4,q>0 reads past wd row end: A zero at k>=132 -- harmless
      short8 bfr = bp[kc*4 + q];
      acc = __builtin_amdgcn_mfma_f32_16x16x32_bf16(afr[kc], bfr, acc, 0, 0, 0);
    }
    int n = nt*16 + col;
    #pragma unroll
    for (int rr = 0; rr < 4; ++rr){
      int lr = q*4 + rr;
      if (n < H_)            cvec[(size_t)(base+i0+lr)*H_ + n] = acc[rr];
      else if (n < H_+NT_)   logit[lr*NT_ + (n-H_)] = acc[rr];
    }
  }
  __syncthreads();
  if (tid < ITILE){
    float mx = -1e30f;
    #pragma unroll
    for (int j=0;j<NT_;++j) mx = fmaxf(mx, logit[tid*NT_+j]);
    float ex[NT_]; float ssum = 0.f;
    #pragma unroll
    for (int j=0;j<NT_;++j){ ex[j] = __expf(logit[tid*NT_+j]-mx); ssum += ex[j]; }
    float inv = __frcp_rn(ssum);
    #pragma unroll
    for (int j=0;j<NT_;++j)
      outp[(size_t)(B_*L_) + (size_t)(base+i0+tid)*NT_ + j] = ex[j]*inv;
  }
}

// ---------------- K4: GAN sampler (R0 structure + tail dedup only) ----------------
// R19: R5's KSTR4=140 broke 16B alignment of the short8 W loads (280B row
// stride): ds_read_b128 split into b64 pairs, lgkm stalls, VALUBusy 92.7->74.6,
// +56us. Bank conflicts (9.2M cyc) are 0.5% of a CU's cycles -- noise. Revert
// to the aligned KSTR=136 image (R0-identical inner loop). Sole delta vs R0:
// tail features 128..131 as ONE full-wave tfpair stream + shfl_xor(16)
// (bit-exact R1-R5), removing 1 of 18 issue-bound RNG streams.
__global__ __launch_bounds__(512, 6) void k4_sampler(
    const uint16_t* __restrict__ wbf, const float* __restrict__ cvec,
    const float* __restrict__ wt, const float* __restrict__ rs,
    float* __restrict__ outmean){
  __shared__ __align__(16) short Wlds[WBF_N + 32];  // +32: slack for kc=4 tail over-read
  __shared__ __align__(16) float clds[16*CSTR];
  __shared__ float wtlds[HPAD];
  __shared__ float part[128];
  int tid = threadIdx.x, lane = tid & 63;
  int l0 = blockIdx.x*16, b = blockIdx.y, sch = blockIdx.z;
  int bl0 = b*L_ + l0;

  {   // stage W: flat 2448 x 16B vector copy
    const uint4v* g = (const uint4v*)wbf;
    uint4v* l = (uint4v*)Wlds;
    for (int idx = tid; idx < WBF_N/8; idx += 512) l[idx] = g[idx];
  }
  for (int m = tid>>6; m < 16; m += 8){
    for (int n = lane; n < CSTR; n += 64){
      float v = 0.f;
      if (n < H_) v = cvec[(size_t)(bl0+m)*H_ + n] - rs[n];
      clds[m*CSTR + n] = v;
    }
  }
  if (tid < HPAD) wtlds[tid] = (tid < H_) ? wt[tid] : 0.f;
  if (tid < 128) part[tid] = 0.f;
  __syncthreads();

  int wave = tid >> 6;
  int q = lane >> 4, col = lane & 15;
  int s = sch*8 + wave;
  if (s < SMP_){
    uint32_t fbase = (uint32_t)(bl0 + col)*(uint32_t)(SMP_*H_)
                   + (uint32_t)s*(uint32_t)H_;
    uint32_t fbq = fbase + (uint32_t)(q*8);
    uint4v afu[KCH];
    #pragma unroll
    for (int kc = 0; kc < 4; ++kc){
      #pragma unroll
      for (int t = 0; t < 4; ++t)
        afu[kc][t] = tfpair(fbq + (uint32_t)(kc*32 + 2*t),
                            fbq + (uint32_t)(kc*32 + 2*t + 1));
    }
    {   // tail features 128..131: one full-wave stream (q even:128/129, q odd:130/131)
      uint32_t ft = fbase + 128u + (uint32_t)((q & 1)*2);
      uint32_t w  = tfpair(ft, ft + 1u);
      uint32_t wo = (uint32_t)__shfl_xor((int)w, 16, 64);
      uint4v a4 = {0u,0u,0u,0u};
      if (q == 0){ a4[0] = w; a4[1] = wo; }
      afu[4] = a4;
    }
    float racc0=0.f, racc1=0.f, racc2=0.f, racc3=0.f;
    for (int nt = 0; nt < NTIL; ++nt){
      float4v acc = {0.f,0.f,0.f,0.f};
      const short8* bp = (const short8*)&Wlds[(nt*16+col)*KSTR];
      #pragma unroll
      for (int kc = 0; kc < KCH; ++kc){
        short8 bfr = bp[kc*4 + q];
        acc = __builtin_amdgcn_mfma_f32_16x16x32_bf16(
                 __builtin_bit_cast(short8, afu[kc]), bfr, acc, 0, 0, 0);
      }
      int n = nt*16 + col;
      float wv = wtlds[n];
      const float* cb = &clds[(q*4)*CSTR + n];
      racc0 += fmaxf(acc[0] + cb[0*CSTR], 0.f)*wv;
      racc1 += fmaxf(acc[1] + cb[1*CSTR], 0.f)*wv;
      racc2 += fmaxf(acc[2] + cb[2*CSTR], 0.f)*wv;
      racc3 += fmaxf(acc[3] + cb[3*CSTR], 0.f)*wv;
    }
    #pragma unroll
    for (int m = 1; m < 16; m <<= 1){
      racc0 += __shfl_xor(racc0, m, 64);
      racc1 += __shfl_xor(racc1, m, 64);
      racc2 += __shfl_xor(racc2, m, 64);
      racc3 += __shfl_xor(racc3, m, 64);
    }
    if (col == 0){
      part[wave*16 + q*4 + 0] = 0.02f * softplus_f(racc0);
      part[wave*16 + q*4 + 1] = 0.02f * softplus_f(racc1);
      part[wave*16 + q*4 + 2] = 0.02f * softplus_f(racc2);
      part[wave*16 + q*4 + 3] = 0.02f * softplus_f(racc3);
    }
  }
  __syncthreads();
  if (tid < 16){
    float v = 0.f;
    #pragma unroll
    for (int w = 0; w < 8; ++w) v += part[w*16 + tid];
    atomicAdd(&outmean[bl0 + tid], v);
  }
}

// ---------------- launch ----------------
extern "C" void kernel_launch(void* const* d_in, const int* in_sizes, int n_in,
                              void* d_out, int out_size, void* d_ws, size_t ws_size,
                              hipStream_t stream){
  const int*   etype = (const int*)  d_in[0];
  const float* etime = (const float*)d_in[1];
  const float* Wt    = (const float*)d_in[3];
  const float* temb  = (const float*)d_in[4];
  const float* Wg    = (const float*)d_in[5];
  const float* bgp   = (const float*)d_in[6];
  const float* Wl    = (const float*)d_in[7];
  const float* blp   = (const float*)d_in[8];
  const float* gamma = (const float*)d_in[9];
  const float* beta  = (const float*)d_in[10];
  const float* Win   = (const float*)d_in[11];
  const float* Wn    = (const float*)d_in[12];
  const float* wtm   = (const float*)d_in[13];
  const float* Wpred = (const float*)d_in[14];
  float* out = (float*)d_out;

  uint16_t* hvT   = (uint16_t*)d_ws;                        // 32*144*512 shorts
  float*    sc4   = (float*)(hvT + (size_t)B_*HPAD*L_);     // 16384*4 floats
  float*    cvec  = sc4 + (size_t)16384*4;                  // 16384*132 floats
  float*    rs    = cvec + (size_t)16384*H_;                // 132 (+pad to 256)
  uint16_t* wbf   = (uint16_t*)(rs + 256);                  // WBF_N shorts
  uint16_t* wd    = wbf + (size_t)WBF_N;                    // WDROW*KSTR shorts

  k0_embed  <<<dim3(147),     dim3(256), 0, stream>>>(etype, etime, Wt, temb, Wg, Wl,
                                                      Wn, Win, Wpred, hvT, sc4, out, wbf, wd, rs);
  k1_attn   <<<dim3(32,32),   dim3(256), 0, stream>>>(etime, sc4, hvT, wd, bgp, blp,
                                                      gamma, beta, cvec, out);
  k4_sampler<<<dim3(32,32,7), dim3(512), 0, stream>>>(wbf, cvec, wtm, rs, out);
}

// Round 7
// 380.353 us; speedup vs baseline: 1.4172x; 1.0033x over previous
//
#include <hip/hip_runtime.h>
#include <stdint.h>

#define B_   32
#define L_   512
#define DT_  4
#define NT_  20
#define SMP_ 50
#define H_   132
#define HPAD 144      // padded feature rows (9 n-tiles of 16)
#define KSTR 136      // bf16 W-image k-stride (shorts), 272B = 17x16B -> ds_read_b128 aligned
#define KCH  5        // 5 k-chunks of 32 (K padded 132 -> 160)
#define NTIL 9
#define WBF_N (HPAD*KSTR)      // 19584 shorts
#define ITILE 16      // k1 i-rows per block
#define SCSTR 520     // k1 score-row stride (shorts)
#define HIDS  136     // k1 hid row stride (floats)
#define HNLS  160     // k1 fused-decoder hn LDS row stride (shorts)
#define WDROW 160     // [Win;Wpred] image rows (152 used)
#define NTIL3 10      // decoder n-tiles

typedef float  float4v __attribute__((ext_vector_type(4)));
typedef short  short8  __attribute__((ext_vector_type(8)));
typedef unsigned int uint4v __attribute__((ext_vector_type(4)));

#if __has_builtin(__builtin_rotateleft32)
#define ROTL(x,r) __builtin_rotateleft32((x),(r))
#elif __has_builtin(__builtin_amdgcn_alignbit)
#define ROTL(x,r) __builtin_amdgcn_alignbit((x),(x),32u-(r))
#else
#define ROTL(x,r) (((x)<<(r))|((x)>>(32u-(r))))
#endif

// ---------------- threefry2x32, key=(0,42), JAX partitionable 32-bit path ------------
// bits[f] = o0 ^ o1 of threefry2x32((0,42), ctr=(0,f))  [verified R5-R12]
__device__ __forceinline__ uint32_t tfpair(uint32_t fa, uint32_t fb){
  const uint32_t ks1 = 42u;
  const uint32_t ks2 = 0x1BD11BDAu ^ 42u;
  uint32_t a0 = 0u, b0 = 0u, a1 = fa + ks1, b1 = fb + ks1;
#define TFR(r) a0+=a1; b0+=b1; a1=ROTL(a1,(r)); b1=ROTL(b1,(r)); a1^=a0; b1^=b0;
  TFR(13) TFR(15) TFR(26) TFR(6)
  a0+=ks1; a1+=ks2+1u; b0+=ks1; b1+=ks2+1u;
  TFR(17) TFR(29) TFR(16) TFR(24)
  a0+=ks2; a1+=2u;     b0+=ks2; b1+=2u;       // ks0+2
  TFR(13) TFR(15) TFR(26) TFR(6)
  a1+=ks1+3u;          b1+=ks1+3u;            // x0+=ks0 (0)
  TFR(17) TFR(29) TFR(16) TFR(24)
  a0+=ks1; a1+=ks2+4u; b0+=ks1; b1+=ks2+4u;
  TFR(13) TFR(15) TFR(26) TFR(6)
  a0+=ks2; a1+=5u;     b0+=ks2; b1+=5u;       // ks0+5
#undef TFR
  uint32_t Ya = ((a0 ^ a1) >> 9) + 0x3f808000u;   // bf16 bits in [31:16], RHU rounding
  uint32_t Yb = ((b0 ^ b1) >> 9) + 0x3f808000u;
#if __has_builtin(__builtin_amdgcn_perm)
  return __builtin_amdgcn_perm(Ya, Yb, 0x03020706u);  // {Yb.hi16, Ya.hi16}
#else
  return (Yb & 0xffff0000u) | (Ya >> 16);
#endif
}

__device__ __forceinline__ float softplus_fast(float x){
  return fmaxf(x,0.f) + __logf(1.f + __expf(-fabsf(x)));
}

__device__ __forceinline__ float softplus_f(float x){
  return fmaxf(x,0.f) + log1pf(expf(-fabsf(x)));
}

__device__ __forceinline__ short f2bf(float f){   // fp32 -> bf16 RNE
  uint32_t u = __float_as_uint(f);
  u += 0x7fffu + ((u>>16)&1u);
  return (short)(u>>16);
}

__device__ __forceinline__ float bf_round(float f){   // fp32 -> bf16 -> fp32
  uint32_t u = __float_as_uint(f);
  u += 0x7fffu + ((u>>16)&1u);
  u &= 0xffff0000u;
  return __uint_as_float(u);
}

// ---------------- K0: embeddings -> transposed bf16 hvT image (coalesced) -----------
__global__ __launch_bounds__(256) void k0_embed(
    const int* __restrict__ etype, const float* __restrict__ etime,
    const float* __restrict__ Wt,  const float* __restrict__ temb,
    const float* __restrict__ Wg,  const float* __restrict__ Wl,
    const float* __restrict__ Wn,  const float* __restrict__ Win,
    const float* __restrict__ Wpred,
    uint16_t* __restrict__ hvT, float* __restrict__ sc4, float* __restrict__ outmean,
    uint16_t* __restrict__ wbf, uint16_t* __restrict__ wd, float* __restrict__ rs){
  int blk = blockIdx.x, tid = threadIdx.x;
  if (blk < 128){
    __shared__ __align__(16) uint16_t tile[HPAD*128];   // 36864 B
    __shared__ float tvec[128];
    int b = blk >> 2, l0 = (blk & 3)*128;
    int base = b*L_ + l0;
    if (tid < 128) tvec[tid] = etime[base + tid];
    __syncthreads();
    const float M = -0.07195578414202429f;  // -ln(10000)/128
    for (int rep = 0; rep < 32; ++rep){
      int idx = rep*256 + tid;
      int k = idx >> 7, p = idx & 127;
      float dterm = __expf((float)(2*k) * M);
      float ang = (float)(l0 + p) * dterm + tvec[p] * Wt[k];
      float sv, cv;
      sincosf(ang, &sv, &cv);
      tile[k*128 + p]      = (uint16_t)f2bf(sv);
      tile[(64+k)*128 + p] = (uint16_t)f2bf(cv);
    }
    for (int rep = 0; rep < 8; ++rep){
      int idx = rep*256 + tid;
      int r = 128 + (idx >> 7), p = idx & 127;
      uint16_t v = 0;
      if (r < 132){
        int et = etype[base + p];
        v = (uint16_t)f2bf(temb[et*4 + (r-128)]);
      }
      tile[r*128 + p] = v;
    }
    if (tid < 128){
      int bl = base + tid;
      int et = etype[bl];
      float t0 = temb[et*4+0], t1 = temb[et*4+1], t2 = temb[et*4+2], t3 = temb[et*4+3];
      sc4[bl*4+0] = t0*Wg[0]+t1*Wg[1]+t2*Wg[2]+t3*Wg[3];  // dg  (j-side)
      sc4[bl*4+1] = t0*Wg[4]+t1*Wg[5]+t2*Wg[6]+t3*Wg[7];  // dg2 (i-side)
      sc4[bl*4+2] = t0*Wl[0]+t1*Wl[1]+t2*Wl[2]+t3*Wl[3];  // dl
      sc4[bl*4+3] = t0*Wl[4]+t1*Wl[5]+t2*Wl[6]+t3*Wl[7];  // dl2
      outmean[bl] = 0.f;                                   // zero for k4 atomics
    }
    __syncthreads();
    for (int pass = 0; pass < 9; ++pass){
      int r = pass*16 + (tid>>4);
      int c = tid & 15;
      ((uint4v*)(hvT + ((size_t)b*HPAD + r)*L_ + l0))[c] = ((const uint4v*)(tile + r*128))[c];
    }
  } else {
    int pb = blk - 128;                // 0..18
    if (pb < 9){                       // W_noise bf16 image + rowsum(bf16 W)
      for (int e = tid; e < 16*KSTR; e += 256){
        int r = e / KSTR, k = e - r*KSTR;
        int n = pb*16 + r;
        uint16_t v = 0;
        if (n < H_ && k < H_) v = (uint16_t)f2bf(Wn[n*H_ + k]);
        wbf[n*KSTR + k] = v;
      }
      if (tid < 16){
        int n = pb*16 + tid;
        if (n < H_){
          float s = 0.f;
          const float* row = Wn + (size_t)n*H_;
          #pragma unroll 4
          for (int k = 0; k < H_; ++k) s += bf_round(row[k]);
          rs[n] = s;
        }
      }
    } else {                           // [Win; Wpred] bf16 image
      int rb = pb - 9;                 // 0..9
      for (int e = tid; e < 16*KSTR; e += 256){
        int r = e / KSTR, k = e - r*KSTR;
        int n = rb*16 + r;
        uint16_t v = 0;
        if (k < H_){
          if (n < H_)          v = (uint16_t)f2bf(Win[n*H_ + k]);
          else if (n < H_+NT_) v = (uint16_t)f2bf(Wpred[(n-H_)*H_ + k]);
        }
        wd[n*KSTR + k] = v;
      }
    }
  }
}

// ---------------- K1: attention flash-tile + LN + fused decoder --------------------
// R20: causal truncation. Block i0 only needs scores j < i0+15: KTM4 =
// ceil(KTM/4)*4 k-tiles of 32 (avg 10 of 16 -> 37.5% less phase-1/2 work).
// Phase 1 skips j >= KTM4*32 (wave-uniform). Phase 2: KTM4==16 blocks keep the
// R13-proven full-16 batch; smaller blocks run 4-deep-batched chunks (named
// regs, static indexing -- rule #20). Decoder now writes cvec - rs (moved from
// k4, bit-identical; enables k4's clds removal).
__global__ __launch_bounds__(256) void k1_attn(
    const float* __restrict__ etime, const float* __restrict__ sc4,
    const uint16_t* __restrict__ hvT, const uint16_t* __restrict__ wd,
    const float* __restrict__ bgp, const float* __restrict__ blp,
    const float* __restrict__ gamma, const float* __restrict__ beta,
    const float* __restrict__ rs,
    float* __restrict__ cvec, float* __restrict__ outp){
  __shared__ __align__(16) uint16_t scb[ITILE*SCSTR];
  __shared__ float jt[L_], jg[L_], jl[L_];
  __shared__ float rt[ITILE], rg[ITILE], rl[ITILE];
  __shared__ __align__(16) float hid[ITILE*HIDS];
  __shared__ __align__(16) uint16_t hnl[ITILE*HNLS];
  __shared__ float logit[ITILE*NT_];
  __shared__ float mur[ITILE], rsr[ITILE];
  int i0 = blockIdx.x*ITILE, b = blockIdx.y, base = b*L_;
  int tid = threadIdx.x;
  float bg = bgp[0], blv = blp[0];
  int KTM4 = (((i0 + 14) >> 5) + 4) & ~3;   // 4..16 k-tiles actually needed (rounded to 4)
  int JMAX4 = KTM4 << 5;                    // 128..512
  for (int j = tid; j < L_; j += 256){
    jt[j] = etime[base+j];
    jg[j] = sc4[(base+j)*4+0];
    jl[j] = sc4[(base+j)*4+2];
  }
  if (tid < ITILE){
    rt[tid] = etime[base+i0+tid];
    rg[tid] = sc4[(base+i0+tid)*4+1];
    rl[tid] = sc4[(base+i0+tid)*4+3];
  }
  __syncthreads();
  // phase 1: score tile, truncated at JMAX4 (j >= JMAX4 never read by MFMA)
  for (int e = tid; e < ITILE*L_; e += 256){
    int r = e >> 9, j = e & (L_-1);
    if (j >= JMAX4) continue;                 // wave-uniform skip
    float v = 0.f;
    if (j < i0 + r){
      float gate = __frcp_rn(1.f + __expf(-(jg[j] + rg[r] + bg)));
      float ls   = softplus_fast(jl[j] + rl[r] + blv) + 1e-6f;
      float d    = rt[r] - jt[j];
      float t2   = 2.f*ls*ls;
      v = gate * t2 * __frcp_rn(t2 + d*d);
    }
    scb[r*SCSTR + j] = (uint16_t)f2bf(v);
  }
  __syncthreads();
  // phase 2: hidden[16][H] = scores @ hv  (MFMA 16x16x32, B from hvT short8)
  int wave = tid>>6, lane = tid&63, q = lane>>4, col = lane&15;
  for (int nt = wave; nt < NTIL; nt += 4){
    int n = nt*16 + col;
    const uint16_t* bT = hvT + ((size_t)b*HPAD + n)*L_;   // 144 rows, pad rows zero
    float4v acc = {0.f,0.f,0.f,0.f};
    if (KTM4 == 16){
      // heavy blocks: R13 path -- all 16 independent B-loads in flight
      short8 bfr[16];
      #pragma unroll
      for (int kt = 0; kt < 16; ++kt)
        bfr[kt] = *(const short8*)&bT[kt*32 + q*8];
      #pragma unroll
      for (int kt = 0; kt < 16; ++kt){
        short8 af = *(const short8*)&scb[col*SCSTR + kt*32 + q*8];
        acc = __builtin_amdgcn_mfma_f32_16x16x32_bf16(af, bfr[kt], acc, 0, 0, 0);
      }
    } else {
      for (int ktc = 0; ktc < KTM4; ktc += 4){
        const uint16_t* bc = bT + ktc*32 + q*8;
        short8 b0 = *(const short8*)&bc[0];
        short8 b1 = *(const short8*)&bc[32];
        short8 b2 = *(const short8*)&bc[64];
        short8 b3 = *(const short8*)&bc[96];
        const uint16_t* ac = scb + col*SCSTR + ktc*32 + q*8;
        acc = __builtin_amdgcn_mfma_f32_16x16x32_bf16(*(const short8*)&ac[0],  b0, acc, 0, 0, 0);
        acc = __builtin_amdgcn_mfma_f32_16x16x32_bf16(*(const short8*)&ac[32], b1, acc, 0, 0, 0);
        acc = __builtin_amdgcn_mfma_f32_16x16x32_bf16(*(const short8*)&ac[64], b2, acc, 0, 0, 0);
        acc = __builtin_amdgcn_mfma_f32_16x16x32_bf16(*(const short8*)&ac[96], b3, acc, 0, 0, 0);
      }
    }
    if (n < H_){
      #pragma unroll
      for (int rr = 0; rr < 4; ++rr)
        hid[(q*4+rr)*HIDS + n] = acc[rr];    // C/D: row=q*4+rr, col=n
    }
  }
  __syncthreads();
  // LayerNorm stats
  #pragma unroll
  for (int rr = 0; rr < 4; ++rr){
    int r = wave*4 + rr;
    float x0 = hid[r*HIDS + lane];
    float x1 = hid[r*HIDS + 64 + lane];
    float x2 = (lane<4) ? hid[r*HIDS + 128 + lane] : 0.f;
    float s1 = x0+x1+x2, s2 = x0*x0+x1*x1+x2*x2;
    #pragma unroll
    for (int m=32; m; m>>=1){ s1 += __shfl_xor(s1, m, 64); s2 += __shfl_xor(s2, m, 64); }
    if (lane == 0){
      float mu = s1 * (1.f/132.f);
      float var = s2 * (1.f/132.f) - mu*mu;
      mur[r] = mu; rsr[r] = rsqrtf(var + 1e-6f);
    }
  }
  __syncthreads();
  if (tid < HNLS){
    if (tid < H_){
      float g = gamma[tid], be = beta[tid];
      #pragma unroll 4
      for (int r = 0; r < ITILE; ++r)
        hnl[r*HNLS + tid] = (uint16_t)f2bf((hid[r*HIDS+tid]-mur[r])*rsr[r]*g + be);
    } else {
      #pragma unroll 4
      for (int r = 0; r < ITILE; ++r) hnl[r*HNLS + tid] = 0;
    }
  }
  __syncthreads();
  // fused decoder: hn(16x132) @ wd(152x132)^T -> (cvec - rs) + logits
  short8 afr[KCH];
  #pragma unroll
  for (int kc = 0; kc < KCH; ++kc)
    afr[kc] = *(const short8*)&hnl[col*HNLS + kc*32 + q*8];   // A[m=col][k]
  for (int nt = wave; nt < NTIL3; nt += 4){
    float4v acc = {0.f,0.f,0.f,0.f};
    const short8* bp = (const short8*)&wd[(nt*16+col)*KSTR];
    #pragma unroll
    for (int kc = 0; kc < KCH; ++kc){
      // kc=4,q>0 reads past wd row end: A zero at k>=132 -- harmless
      short8 bfr = bp[kc*4 + q];
      acc = __builtin_amdgcn_mfma_f32_16x16x32_bf16(afr[kc], bfr, acc, 0, 0, 0);
    }
    int n = nt*16 + col;
    #pragma unroll
    for (int rr = 0; rr < 4; ++rr){
      int lr = q*4 + rr;
      if (n < H_)            cvec[(size_t)(base+i0+lr)*H_ + n] = acc[rr] - rs[n];
      else if (n < H_+NT_)   logit[lr*NT_ + (n-H_)] = acc[rr];
    }
  }
  __syncthreads();
  if (tid < ITILE){
    float mx = -1e30f;
    #pragma unroll
    for (int j=0;j<NT_;++j) mx = fmaxf(mx, logit[tid*NT_+j]);
    float ex[NT_]; float ssum = 0.f;
    #pragma unroll
    for (int j=0;j<NT_;++j){ ex[j] = __expf(logit[tid*NT_+j]-mx); ssum += ex[j]; }
    float inv = __frcp_rn(ssum);
    #pragma unroll
    for (int j=0;j<NT_;++j)
      outp[(size_t)(B_*L_) + (size_t)(base+i0+tid)*NT_ + j] = ex[j]*inv;
  }
}

// ---------------- K4: GAN sampler (R6 structure, clds -> direct cvec reads) --------
// R20: drop clds (9.5KB): LDS 50.2KB -> 40.3KB crosses the 40.96KB threshold ->
// 4 blocks/CU = 32 waves (was 3/24, Occupancy 66%). cvec arrives pre-subtracted
// (k1 does -rs). Epilogue reads the 4 cb floats per nt from L2-resident cvec
// (coalesced over col; n>=132 lands in adjacent finite ws data x wv=0 -> 0).
// launch_bounds(512,4) -> VGPR cap 64 (empirical cap = 512/(2*arg)); body needs
// ~40 + ~16 epilogue-live -> no spill expected (watch WRITE_SIZE).
__global__ __launch_bounds__(512, 4) void k4_sampler(
    const uint16_t* __restrict__ wbf, const float* __restrict__ cvec,
    const float* __restrict__ wt, float* __restrict__ outmean){
  __shared__ __align__(16) short Wlds[WBF_N + 32];  // +32: slack for kc=4 tail over-read
  __shared__ float wtlds[HPAD];
  __shared__ float part[128];
  int tid = threadIdx.x, lane = tid & 63;
  int l0 = blockIdx.x*16, b = blockIdx.y, sch = blockIdx.z;
  int bl0 = b*L_ + l0;

  {   // stage W (incl. slack words -- keeps kc=4 over-read finite): 2452 x 16B
    const uint4v* g = (const uint4v*)wbf;
    uint4v* l = (uint4v*)Wlds;
    for (int idx = tid; idx < (WBF_N+32)/8; idx += 512) l[idx] = g[idx];
  }
  if (tid < HPAD) wtlds[tid] = (tid < H_) ? wt[tid] : 0.f;
  if (tid < 128) part[tid] = 0.f;
  __syncthreads();

  int wave = tid >> 6;
  int q = lane >> 4, col = lane & 15;
  int s = sch*8 + wave;
  if (s < SMP_){
    uint32_t fbase = (uint32_t)(bl0 + col)*(uint32_t)(SMP_*H_)
                   + (uint32_t)s*(uint32_t)H_;
    uint32_t fbq = fbase + (uint32_t)(q*8);
    uint4v afu[KCH];
    #pragma unroll
    for (int kc = 0; kc < 4; ++kc){
      #pragma unroll
      for (int t = 0; t < 4; ++t)
        afu[kc][t] = tfpair(fbq + (uint32_t)(kc*32 + 2*t),
                            fbq + (uint32_t)(kc*32 + 2*t + 1));
    }
    {   // tail features 128..131: one full-wave stream (q even:128/129, q odd:130/131)
      uint32_t ft = fbase + 128u + (uint32_t)((q & 1)*2);
      uint32_t w  = tfpair(ft, ft + 1u);
      uint32_t wo = (uint32_t)__shfl_xor((int)w, 16, 64);
      uint4v a4 = {0u,0u,0u,0u};
      if (q == 0){ a4[0] = w; a4[1] = wo; }
      afu[4] = a4;
    }
    const float* cbase = cvec + (size_t)(bl0 + q*4)*H_;
    float racc0=0.f, racc1=0.f, racc2=0.f, racc3=0.f;
    for (int nt = 0; nt < NTIL; ++nt){
      float4v acc = {0.f,0.f,0.f,0.f};
      const short8* bp = (const short8*)&Wlds[(nt*16+col)*KSTR];
      #pragma unroll
      for (int kc = 0; kc < KCH; ++kc){
        short8 bfr = bp[kc*4 + q];
        acc = __builtin_amdgcn_mfma_f32_16x16x32_bf16(
                 __builtin_bit_cast(short8, afu[kc]), bfr, acc, 0, 0, 0);
      }
      int n = nt*16 + col;
      float wv = wtlds[n];
      const float* cb = cbase + n;
      racc0 += fmaxf(acc[0] + cb[0*H_], 0.f)*wv;
      racc1 += fmaxf(acc[1] + cb[1*H_], 0.f)*wv;
      racc2 += fmaxf(acc[2] + cb[2*H_], 0.f)*wv;
      racc3 += fmaxf(acc[3] + cb[3*H_], 0.f)*wv;
    }
    #pragma unroll
    for (int m = 1; m < 16; m <<= 1){
      racc0 += __shfl_xor(racc0, m, 64);
      racc1 += __shfl_xor(racc1, m, 64);
      racc2 += __shfl_xor(racc2, m, 64);
      racc3 += __shfl_xor(racc3, m, 64);
    }
    if (col == 0){
      part[wave*16 + q*4 + 0] = 0.02f * softplus_f(racc0);
      part[wave*16 + q*4 + 1] = 0.02f * softplus_f(racc1);
      part[wave*16 + q*4 + 2] = 0.02f * softplus_f(racc2);
      part[wave*16 + q*4 + 3] = 0.02f * softplus_f(racc3);
    }
  }
  __syncthreads();
  if (tid < 16){
    float v = 0.f;
    #pragma unroll
    for (int w = 0; w < 8; ++w) v += part[w*16 + tid];
    atomicAdd(&outmean[bl0 + tid], v);
  }
}

// ---------------- launch ----------------
extern "C" void kernel_launch(void* const* d_in, const int* in_sizes, int n_in,
                              void* d_out, int out_size, void* d_ws, size_t ws_size,
                              hipStream_t stream){
  const int*   etype = (const int*)  d_in[0];
  const float* etime = (const float*)d_in[1];
  const float* Wt    = (const float*)d_in[3];
  const float* temb  = (const float*)d_in[4];
  const float* Wg    = (const float*)d_in[5];
  const float* bgp   = (const float*)d_in[6];
  const float* Wl    = (const float*)d_in[7];
  const float* blp   = (const float*)d_in[8];
  const float* gamma = (const float*)d_in[9];
  const float* beta  = (const float*)d_in[10];
  const float* Win   = (const float*)d_in[11];
  const float* Wn    = (const float*)d_in[12];
  const float* wtm   = (const float*)d_in[13];
  const float* Wpred = (const float*)d_in[14];
  float* out = (float*)d_out;

  uint16_t* hvT   = (uint16_t*)d_ws;                        // 32*144*512 shorts
  float*    sc4   = (float*)(hvT + (size_t)B_*HPAD*L_);     // 16384*4 floats
  float*    cvec  = sc4 + (size_t)16384*4;                  // 16384*132 floats
  float*    rs    = cvec + (size_t)16384*H_;                // 132 (+pad to 256)
  uint16_t* wbf   = (uint16_t*)(rs + 256);                  // WBF_N shorts
  uint16_t* wd    = wbf + (size_t)WBF_N;                    // WDROW*KSTR shorts

  k0_embed  <<<dim3(147),     dim3(256), 0, stream>>>(etype, etime, Wt, temb, Wg, Wl,
                                                      Wn, Win, Wpred, hvT, sc4, out, wbf, wd, rs);
  k1_attn   <<<dim3(32,32),   dim3(256), 0, stream>>>(etime, sc4, hvT, wd, bgp, blp,
                                                      gamma, beta, rs, cvec, out);
  k4_sampler<<<dim3(32,32,7), dim3(512), 0, stream>>>(wbf, cvec, wtm, out);
}

// Round 8
// 358.970 us; speedup vs baseline: 1.5016x; 1.0596x over previous
//
#include <hip/hip_runtime.h>
#include <stdint.h>

#define B_   32
#define L_   512
#define DT_  4
#define NT_  20
#define SMP_ 50
#define H_   132
#define HPAD 144      // padded feature rows (9 n-tiles of 16)
#define KSTR 136      // bf16 W-image k-stride (shorts), 272B = 17x16B -> ds_read_b128 aligned
#define KCH  5        // 5 k-chunks of 32 (K padded 132 -> 160)
#define NTIL 9
#define WBF_N (HPAD*KSTR)      // 19584 shorts
#define ITILE 16      // k1 i-rows per block
#define SCSTR 520     // k1 score-row stride (shorts)
#define HIDS  136     // k1 hid row stride (floats)
#define HNLS  160     // k1 fused-decoder hn LDS row stride (shorts)
#define WDROW 160     // [Win;Wpred] image rows (152 used)
#define NTIL3 10      // decoder n-tiles
#define EBLK 512      // k0 embed blocks (32 positions each)
#define EPOS 32       // positions per embed block

typedef float  float4v __attribute__((ext_vector_type(4)));
typedef short  short8  __attribute__((ext_vector_type(8)));
typedef unsigned int uint4v __attribute__((ext_vector_type(4)));

#if __has_builtin(__builtin_rotateleft32)
#define ROTL(x,r) __builtin_rotateleft32((x),(r))
#elif __has_builtin(__builtin_amdgcn_alignbit)
#define ROTL(x,r) __builtin_amdgcn_alignbit((x),(x),32u-(r))
#else
#define ROTL(x,r) (((x)<<(r))|((x)>>(32u-(r))))
#endif

// ---------------- threefry2x32, key=(0,42), JAX partitionable 32-bit path ------------
// bits[f] = o0 ^ o1 of threefry2x32((0,42), ctr=(0,f))  [verified R5-R12]
__device__ __forceinline__ uint32_t tfpair(uint32_t fa, uint32_t fb){
  const uint32_t ks1 = 42u;
  const uint32_t ks2 = 0x1BD11BDAu ^ 42u;
  uint32_t a0 = 0u, b0 = 0u, a1 = fa + ks1, b1 = fb + ks1;
#define TFR(r) a0+=a1; b0+=b1; a1=ROTL(a1,(r)); b1=ROTL(b1,(r)); a1^=a0; b1^=b0;
  TFR(13) TFR(15) TFR(26) TFR(6)
  a0+=ks1; a1+=ks2+1u; b0+=ks1; b1+=ks2+1u;
  TFR(17) TFR(29) TFR(16) TFR(24)
  a0+=ks2; a1+=2u;     b0+=ks2; b1+=2u;       // ks0+2
  TFR(13) TFR(15) TFR(26) TFR(6)
  a1+=ks1+3u;          b1+=ks1+3u;            // x0+=ks0 (0)
  TFR(17) TFR(29) TFR(16) TFR(24)
  a0+=ks1; a1+=ks2+4u; b0+=ks1; b1+=ks2+4u;
  TFR(13) TFR(15) TFR(26) TFR(6)
  a0+=ks2; a1+=5u;     b0+=ks2; b1+=5u;       // ks0+5
#undef TFR
  uint32_t Ya = ((a0 ^ a1) >> 9) + 0x3f808000u;   // bf16 bits in [31:16], RHU rounding
  uint32_t Yb = ((b0 ^ b1) >> 9) + 0x3f808000u;
#if __has_builtin(__builtin_amdgcn_perm)
  return __builtin_amdgcn_perm(Ya, Yb, 0x03020706u);  // {Yb.hi16, Ya.hi16}
#else
  return (Yb & 0xffff0000u) | (Ya >> 16);
#endif
}

__device__ __forceinline__ float softplus_fast(float x){
  return fmaxf(x,0.f) + __logf(1.f + __expf(-fabsf(x)));
}

__device__ __forceinline__ short f2bf(float f){   // fp32 -> bf16 RNE
  uint32_t u = __float_as_uint(f);
  u += 0x7fffu + ((u>>16)&1u);
  return (short)(u>>16);
}

__device__ __forceinline__ float bf_round(float f){   // fp32 -> bf16 -> fp32
  uint32_t u = __float_as_uint(f);
  u += 0x7fffu + ((u>>16)&1u);
  u &= 0xffff0000u;
  return __uint_as_float(u);
}

// ---------------- K0: embeddings -> transposed bf16 hvT image (coalesced) -----------
// R21: embed tile split 128 -> 32 positions/block (147 -> 531 blocks). R7 showed
// k1 compute is ~free; the non-k4 92us is k0-dominated: 147 blocks left 40% of
// CUs idle and 4 waves/CU couldn't hide the serial precise-sincosf chains.
// Per-element arithmetic unchanged (bit-identical output, new block mapping).
__global__ __launch_bounds__(256) void k0_embed(
    const int* __restrict__ etype, const float* __restrict__ etime,
    const float* __restrict__ Wt,  const float* __restrict__ temb,
    const float* __restrict__ Wg,  const float* __restrict__ Wl,
    const float* __restrict__ Wn,  const float* __restrict__ Win,
    const float* __restrict__ Wpred,
    uint16_t* __restrict__ hvT, float* __restrict__ sc4, float* __restrict__ outmean,
    uint16_t* __restrict__ wbf, uint16_t* __restrict__ wd, float* __restrict__ rs){
  int blk = blockIdx.x, tid = threadIdx.x;
  if (blk < EBLK){
    __shared__ __align__(16) uint16_t tile[HPAD*EPOS];   // 9216 B
    __shared__ float tvec[EPOS];
    int b = blk >> 4, l0 = (blk & 15)*EPOS;
    int base = b*L_ + l0;
    if (tid < EPOS) tvec[tid] = etime[base + tid];
    __syncthreads();
    const float M = -0.07195578414202429f;  // -ln(10000)/128
    #pragma unroll
    for (int rep = 0; rep < 8; ++rep){      // 64 k x 32 p = 2048 elems
      int idx = rep*256 + tid;
      int k = idx >> 5, p = idx & (EPOS-1);
      float dterm = __expf((float)(2*k) * M);
      float ang = (float)(l0 + p) * dterm + tvec[p] * Wt[k];
      float sv, cv;
      sincosf(ang, &sv, &cv);
      tile[k*EPOS + p]      = (uint16_t)f2bf(sv);
      tile[(64+k)*EPOS + p] = (uint16_t)f2bf(cv);
    }
    if (tid < 128){                          // type rows 128..131 x 32 p
      int r = 128 + (tid >> 5), p = tid & (EPOS-1);
      int et = etype[base + p];
      tile[r*EPOS + p] = (uint16_t)f2bf(temb[et*4 + (r-128)]);
    } else if (tid < 128 + 4*EPOS){          // zero pad rows 132..143
      int e = tid - 128;
      // covered below by explicit pad loop
    }
    // pad rows 132..143 zero (12 rows x 32)
    for (int e = tid; e < 12*EPOS; e += 256)
      tile[(H_ + (e >> 5))*EPOS + (e & (EPOS-1))] = 0;
    if (tid < EPOS){
      int bl = base + tid;
      int et = etype[bl];
      float t0 = temb[et*4+0], t1 = temb[et*4+1], t2 = temb[et*4+2], t3 = temb[et*4+3];
      sc4[bl*4+0] = t0*Wg[0]+t1*Wg[1]+t2*Wg[2]+t3*Wg[3];  // dg  (j-side)
      sc4[bl*4+1] = t0*Wg[4]+t1*Wg[5]+t2*Wg[6]+t3*Wg[7];  // dg2 (i-side)
      sc4[bl*4+2] = t0*Wl[0]+t1*Wl[1]+t2*Wl[2]+t3*Wl[3];  // dl
      sc4[bl*4+3] = t0*Wl[4]+t1*Wl[5]+t2*Wl[6]+t3*Wl[7];  // dl2
      outmean[bl] = 0.f;                                   // zero for k4 atomics
    }
    __syncthreads();
    // writeout: 144 rows x 64B = 576 x 16B chunks
    for (int e = tid; e < HPAD*4; e += 256){
      int r = e >> 2, c = e & 3;
      ((uint4v*)(hvT + ((size_t)b*HPAD + r)*L_ + l0))[c] = ((const uint4v*)(tile + r*EPOS))[c];
    }
  } else {
    int pb = blk - EBLK;               // 0..18
    if (pb < 9){                       // W_noise bf16 image + rowsum(bf16 W)
      for (int e = tid; e < 16*KSTR; e += 256){
        int r = e / KSTR, k = e - r*KSTR;
        int n = pb*16 + r;
        uint16_t v = 0;
        if (n < H_ && k < H_) v = (uint16_t)f2bf(Wn[n*H_ + k]);
        wbf[n*KSTR + k] = v;
      }
      if (tid < 16){
        int n = pb*16 + tid;
        if (n < H_){
          float s = 0.f;
          const float* row = Wn + (size_t)n*H_;
          #pragma unroll 4
          for (int k = 0; k < H_; ++k) s += bf_round(row[k]);
          rs[n] = s;
        }
      }
    } else {                           // [Win; Wpred] bf16 image
      int rb = pb - 9;                 // 0..9
      for (int e = tid; e < 16*KSTR; e += 256){
        int r = e / KSTR, k = e - r*KSTR;
        int n = rb*16 + r;
        uint16_t v = 0;
        if (k < H_){
          if (n < H_)          v = (uint16_t)f2bf(Win[n*H_ + k]);
          else if (n < H_+NT_) v = (uint16_t)f2bf(Wpred[(n-H_)*H_ + k]);
        }
        wd[n*KSTR + k] = v;
      }
    }
  }
}

// ---------------- K1: attention flash-tile + LN + fused decoder --------------------
// R20: causal truncation (KTM4 k-tiles). Decoder writes cvec - rs.
__global__ __launch_bounds__(256) void k1_attn(
    const float* __restrict__ etime, const float* __restrict__ sc4,
    const uint16_t* __restrict__ hvT, const uint16_t* __restrict__ wd,
    const float* __restrict__ bgp, const float* __restrict__ blp,
    const float* __restrict__ gamma, const float* __restrict__ beta,
    const float* __restrict__ rs,
    float* __restrict__ cvec, float* __restrict__ outp){
  __shared__ __align__(16) uint16_t scb[ITILE*SCSTR];
  __shared__ float jt[L_], jg[L_], jl[L_];
  __shared__ float rt[ITILE], rg[ITILE], rl[ITILE];
  __shared__ __align__(16) float hid[ITILE*HIDS];
  __shared__ __align__(16) uint16_t hnl[ITILE*HNLS];
  __shared__ float logit[ITILE*NT_];
  __shared__ float mur[ITILE], rsr[ITILE];
  int i0 = blockIdx.x*ITILE, b = blockIdx.y, base = b*L_;
  int tid = threadIdx.x;
  float bg = bgp[0], blv = blp[0];
  int KTM4 = (((i0 + 14) >> 5) + 4) & ~3;   // 4..16 k-tiles actually needed (rounded to 4)
  int JMAX4 = KTM4 << 5;                    // 128..512
  for (int j = tid; j < L_; j += 256){
    jt[j] = etime[base+j];
    jg[j] = sc4[(base+j)*4+0];
    jl[j] = sc4[(base+j)*4+2];
  }
  if (tid < ITILE){
    rt[tid] = etime[base+i0+tid];
    rg[tid] = sc4[(base+i0+tid)*4+1];
    rl[tid] = sc4[(base+i0+tid)*4+3];
  }
  __syncthreads();
  // phase 1: score tile, truncated at JMAX4 (j >= JMAX4 never read by MFMA)
  for (int e = tid; e < ITILE*L_; e += 256){
    int r = e >> 9, j = e & (L_-1);
    if (j >= JMAX4) continue;                 // wave-uniform skip
    float v = 0.f;
    if (j < i0 + r){
      float gate = __frcp_rn(1.f + __expf(-(jg[j] + rg[r] + bg)));
      float ls   = softplus_fast(jl[j] + rl[r] + blv) + 1e-6f;
      float d    = rt[r] - jt[j];
      float t2   = 2.f*ls*ls;
      v = gate * t2 * __frcp_rn(t2 + d*d);
    }
    scb[r*SCSTR + j] = (uint16_t)f2bf(v);
  }
  __syncthreads();
  // phase 2: hidden[16][H] = scores @ hv  (MFMA 16x16x32, B from hvT short8)
  int wave = tid>>6, lane = tid&63, q = lane>>4, col = lane&15;
  for (int nt = wave; nt < NTIL; nt += 4){
    int n = nt*16 + col;
    const uint16_t* bT = hvT + ((size_t)b*HPAD + n)*L_;   // 144 rows, pad rows zero
    float4v acc = {0.f,0.f,0.f,0.f};
    if (KTM4 == 16){
      // heavy blocks: R13 path -- all 16 independent B-loads in flight
      short8 bfr[16];
      #pragma unroll
      for (int kt = 0; kt < 16; ++kt)
        bfr[kt] = *(const short8*)&bT[kt*32 + q*8];
      #pragma unroll
      for (int kt = 0; kt < 16; ++kt){
        short8 af = *(const short8*)&scb[col*SCSTR + kt*32 + q*8];
        acc = __builtin_amdgcn_mfma_f32_16x16x32_bf16(af, bfr[kt], acc, 0, 0, 0);
      }
    } else {
      for (int ktc = 0; ktc < KTM4; ktc += 4){
        const uint16_t* bc = bT + ktc*32 + q*8;
        short8 b0 = *(const short8*)&bc[0];
        short8 b1 = *(const short8*)&bc[32];
        short8 b2 = *(const short8*)&bc[64];
        short8 b3 = *(const short8*)&bc[96];
        const uint16_t* ac = scb + col*SCSTR + ktc*32 + q*8;
        acc = __builtin_amdgcn_mfma_f32_16x16x32_bf16(*(const short8*)&ac[0],  b0, acc, 0, 0, 0);
        acc = __builtin_amdgcn_mfma_f32_16x16x32_bf16(*(const short8*)&ac[32], b1, acc, 0, 0, 0);
        acc = __builtin_amdgcn_mfma_f32_16x16x32_bf16(*(const short8*)&ac[64], b2, acc, 0, 0, 0);
        acc = __builtin_amdgcn_mfma_f32_16x16x32_bf16(*(const short8*)&ac[96], b3, acc, 0, 0, 0);
      }
    }
    if (n < H_){
      #pragma unroll
      for (int rr = 0; rr < 4; ++rr)
        hid[(q*4+rr)*HIDS + n] = acc[rr];    // C/D: row=q*4+rr, col=n
    }
  }
  __syncthreads();
  // LayerNorm stats
  #pragma unroll
  for (int rr = 0; rr < 4; ++rr){
    int r = wave*4 + rr;
    float x0 = hid[r*HIDS + lane];
    float x1 = hid[r*HIDS + 64 + lane];
    float x2 = (lane<4) ? hid[r*HIDS + 128 + lane] : 0.f;
    float s1 = x0+x1+x2, s2 = x0*x0+x1*x1+x2*x2;
    #pragma unroll
    for (int m=32; m; m>>=1){ s1 += __shfl_xor(s1, m, 64); s2 += __shfl_xor(s2, m, 64); }
    if (lane == 0){
      float mu = s1 * (1.f/132.f);
      float var = s2 * (1.f/132.f) - mu*mu;
      mur[r] = mu; rsr[r] = rsqrtf(var + 1e-6f);
    }
  }
  __syncthreads();
  if (tid < HNLS){
    if (tid < H_){
      float g = gamma[tid], be = beta[tid];
      #pragma unroll 4
      for (int r = 0; r < ITILE; ++r)
        hnl[r*HNLS + tid] = (uint16_t)f2bf((hid[r*HIDS+tid]-mur[r])*rsr[r]*g + be);
    } else {
      #pragma unroll 4
      for (int r = 0; r < ITILE; ++r) hnl[r*HNLS + tid] = 0;
    }
  }
  __syncthreads();
  // fused decoder: hn(16x132) @ wd(152x132)^T -> (cvec - rs) + logits
  short8 afr[KCH];
  #pragma unroll
  for (int kc = 0; kc < KCH; ++kc)
    afr[kc] = *(const short8*)&hnl[col*HNLS + kc*32 + q*8];   // A[m=col][k]
  for (int nt = wave; nt < NTIL3; nt += 4){
    float4v acc = {0.f,0.f,0.f,0.f};
    const short8* bp = (const short8*)&wd[(nt*16+col)*KSTR];
    #pragma unroll
    for (int kc = 0; kc < KCH; ++kc){
      // kc=4,q>0 reads past wd row end: A zero at k>=132 -- harmless
      short8 bfr = bp[kc*4 + q];
      acc = __builtin_amdgcn_mfma_f32_16x16x32_bf16(afr[kc], bfr, acc, 0, 0, 0);
    }
    int n = nt*16 + col;
    #pragma unroll
    for (int rr = 0; rr < 4; ++rr){
      int lr = q*4 + rr;
      if (n < H_)            cvec[(size_t)(base+i0+lr)*H_ + n] = acc[rr] - rs[n];
      else if (n < H_+NT_)   logit[lr*NT_ + (n-H_)] = acc[rr];
    }
  }
  __syncthreads();
  if (tid < ITILE){
    float mx = -1e30f;
    #pragma unroll
    for (int j=0;j<NT_;++j) mx = fmaxf(mx, logit[tid*NT_+j]);
    float ex[NT_]; float ssum = 0.f;
    #pragma unroll
    for (int j=0;j<NT_;++j){ ex[j] = __expf(logit[tid*NT_+j]-mx); ssum += ex[j]; }
    float inv = __frcp_rn(ssum);
    #pragma unroll
    for (int j=0;j<NT_;++j)
      outp[(size_t)(B_*L_) + (size_t)(base+i0+tid)*NT_ + j] = ex[j]*inv;
  }
}

// ---------------- K4: GAN sampler (R7 structure + fast softplus) -------------------
// R21: softplus_f -> softplus_fast in the 4 epilogue calls (precise log1pf/expf
// were ~100-150 slow-path insts per thread-sample in an issue-bound kernel;
// error ~1e-6 << the 2^-8 bf16 floor absmax sits at). Rest identical to R7.
__global__ __launch_bounds__(512, 4) void k4_sampler(
    const uint16_t* __restrict__ wbf, const float* __restrict__ cvec,
    const float* __restrict__ wt, float* __restrict__ outmean){
  __shared__ __align__(16) short Wlds[WBF_N + 32];  // +32: slack for kc=4 tail over-read
  __shared__ float wtlds[HPAD];
  __shared__ float part[128];
  int tid = threadIdx.x, lane = tid & 63;
  int l0 = blockIdx.x*16, b = blockIdx.y, sch = blockIdx.z;
  int bl0 = b*L_ + l0;

  {   // stage W (incl. slack words -- keeps kc=4 over-read finite): 2452 x 16B
    const uint4v* g = (const uint4v*)wbf;
    uint4v* l = (uint4v*)Wlds;
    for (int idx = tid; idx < (WBF_N+32)/8; idx += 512) l[idx] = g[idx];
  }
  if (tid < HPAD) wtlds[tid] = (tid < H_) ? wt[tid] : 0.f;
  if (tid < 128) part[tid] = 0.f;
  __syncthreads();

  int wave = tid >> 6;
  int q = lane >> 4, col = lane & 15;
  int s = sch*8 + wave;
  if (s < SMP_){
    uint32_t fbase = (uint32_t)(bl0 + col)*(uint32_t)(SMP_*H_)
                   + (uint32_t)s*(uint32_t)H_;
    uint32_t fbq = fbase + (uint32_t)(q*8);
    uint4v afu[KCH];
    #pragma unroll
    for (int kc = 0; kc < 4; ++kc){
      #pragma unroll
      for (int t = 0; t < 4; ++t)
        afu[kc][t] = tfpair(fbq + (uint32_t)(kc*32 + 2*t),
                            fbq + (uint32_t)(kc*32 + 2*t + 1));
    }
    {   // tail features 128..131: one full-wave stream (q even:128/129, q odd:130/131)
      uint32_t ft = fbase + 128u + (uint32_t)((q & 1)*2);
      uint32_t w  = tfpair(ft, ft + 1u);
      uint32_t wo = (uint32_t)__shfl_xor((int)w, 16, 64);
      uint4v a4 = {0u,0u,0u,0u};
      if (q == 0){ a4[0] = w; a4[1] = wo; }
      afu[4] = a4;
    }
    const float* cbase = cvec + (size_t)(bl0 + q*4)*H_;
    float racc0=0.f, racc1=0.f, racc2=0.f, racc3=0.f;
    for (int nt = 0; nt < NTIL; ++nt){
      float4v acc = {0.f,0.f,0.f,0.f};
      const short8* bp = (const short8*)&Wlds[(nt*16+col)*KSTR];
      #pragma unroll
      for (int kc = 0; kc < KCH; ++kc){
        short8 bfr = bp[kc*4 + q];
        acc = __builtin_amdgcn_mfma_f32_16x16x32_bf16(
                 __builtin_bit_cast(short8, afu[kc]), bfr, acc, 0, 0, 0);
      }
      int n = nt*16 + col;
      float wv = wtlds[n];
      const float* cb = cbase + n;
      racc0 += fmaxf(acc[0] + cb[0*H_], 0.f)*wv;
      racc1 += fmaxf(acc[1] + cb[1*H_], 0.f)*wv;
      racc2 += fmaxf(acc[2] + cb[2*H_], 0.f)*wv;
      racc3 += fmaxf(acc[3] + cb[3*H_], 0.f)*wv;
    }
    #pragma unroll
    for (int m = 1; m < 16; m <<= 1){
      racc0 += __shfl_xor(racc0, m, 64);
      racc1 += __shfl_xor(racc1, m, 64);
      racc2 += __shfl_xor(racc2, m, 64);
      racc3 += __shfl_xor(racc3, m, 64);
    }
    if (col == 0){
      part[wave*16 + q*4 + 0] = 0.02f * softplus_fast(racc0);
      part[wave*16 + q*4 + 1] = 0.02f * softplus_fast(racc1);
      part[wave*16 + q*4 + 2] = 0.02f * softplus_fast(racc2);
      part[wave*16 + q*4 + 3] = 0.02f * softplus_fast(racc3);
    }
  }
  __syncthreads();
  if (tid < 16){
    float v = 0.f;
    #pragma unroll
    for (int w = 0; w < 8; ++w) v += part[w*16 + tid];
    atomicAdd(&outmean[bl0 + tid], v);
  }
}

// ---------------- launch ----------------
extern "C" void kernel_launch(void* const* d_in, const int* in_sizes, int n_in,
                              void* d_out, int out_size, void* d_ws, size_t ws_size,
                              hipStream_t stream){
  const int*   etype = (const int*)  d_in[0];
  const float* etime = (const float*)d_in[1];
  const float* Wt    = (const float*)d_in[3];
  const float* temb  = (const float*)d_in[4];
  const float* Wg    = (const float*)d_in[5];
  const float* bgp   = (const float*)d_in[6];
  const float* Wl    = (const float*)d_in[7];
  const float* blp   = (const float*)d_in[8];
  const float* gamma = (const float*)d_in[9];
  const float* beta  = (const float*)d_in[10];
  const float* Win   = (const float*)d_in[11];
  const float* Wn    = (const float*)d_in[12];
  const float* wtm   = (const float*)d_in[13];
  const float* Wpred = (const float*)d_in[14];
  float* out = (float*)d_out;

  uint16_t* hvT   = (uint16_t*)d_ws;                        // 32*144*512 shorts
  float*    sc4   = (float*)(hvT + (size_t)B_*HPAD*L_);     // 16384*4 floats
  float*    cvec  = sc4 + (size_t)16384*4;                  // 16384*132 floats
  float*    rs    = cvec + (size_t)16384*H_;                // 132 (+pad to 256)
  uint16_t* wbf   = (uint16_t*)(rs + 256);                  // WBF_N shorts
  uint16_t* wd    = wbf + (size_t)WBF_N;                    // WDROW*KSTR shorts

  k0_embed  <<<dim3(EBLK+19),  dim3(256), 0, stream>>>(etype, etime, Wt, temb, Wg, Wl,
                                                       Wn, Win, Wpred, hvT, sc4, out, wbf, wd, rs);
  k1_attn   <<<dim3(32,32),    dim3(256), 0, stream>>>(etime, sc4, hvT, wd, bgp, blp,
                                                       gamma, beta, rs, cvec, out);
  k4_sampler<<<dim3(32,32,7),  dim3(512), 0, stream>>>(wbf, cvec, wtm, out);
}

// Round 9
// 353.492 us; speedup vs baseline: 1.5248x; 1.0155x over previous
//
#include <hip/hip_runtime.h>
#include <stdint.h>

#define B_   32
#define L_   512
#define DT_  4
#define NT_  20
#define SMP_ 50
#define H_   132
#define HPAD 144      // padded feature rows (9 n-tiles of 16)
#define KSTR 136      // bf16 W-image k-stride (shorts), 272B = 17x16B -> ds_read_b128 aligned
#define KCH  5        // 5 k-chunks of 32 (K padded 132 -> 160)
#define NTIL 9
#define WBF_N (HPAD*KSTR)      // 19584 shorts
#define ITILE 16      // k1 i-rows per block
#define SCSTR 520     // k1 score-row stride (shorts)
#define HIDS  136     // k1 hid row stride (floats)
#define HNLS  160     // k1 fused-decoder hn LDS row stride (shorts)
#define WDROW 160     // [Win;Wpred] image rows (152 used)
#define NTIL3 10      // decoder n-tiles
#define EBLK 512      // k0 embed blocks (32 positions each)
#define EPOS 32       // positions per embed block
#define NP_  16384    // B_*L_ positions (sc4 plane stride)

typedef float  float4v __attribute__((ext_vector_type(4)));
typedef short  short8  __attribute__((ext_vector_type(8)));
typedef unsigned int uint4v __attribute__((ext_vector_type(4)));

#if __has_builtin(__builtin_rotateleft32)
#define ROTL(x,r) __builtin_rotateleft32((x),(r))
#elif __has_builtin(__builtin_amdgcn_alignbit)
#define ROTL(x,r) __builtin_amdgcn_alignbit((x),(x),32u-(r))
#else
#define ROTL(x,r) (((x)<<(r))|((x)>>(32u-(r))))
#endif

// ---------------- threefry2x32, key=(0,42), JAX partitionable 32-bit path ------------
// bits[f] = o0 ^ o1 of threefry2x32((0,42), ctr=(0,f))  [verified R5-R12]
__device__ __forceinline__ uint32_t tfpair(uint32_t fa, uint32_t fb){
  const uint32_t ks1 = 42u;
  const uint32_t ks2 = 0x1BD11BDAu ^ 42u;
  uint32_t a0 = 0u, b0 = 0u, a1 = fa + ks1, b1 = fb + ks1;
#define TFR(r) a0+=a1; b0+=b1; a1=ROTL(a1,(r)); b1=ROTL(b1,(r)); a1^=a0; b1^=b0;
  TFR(13) TFR(15) TFR(26) TFR(6)
  a0+=ks1; a1+=ks2+1u; b0+=ks1; b1+=ks2+1u;
  TFR(17) TFR(29) TFR(16) TFR(24)
  a0+=ks2; a1+=2u;     b0+=ks2; b1+=2u;       // ks0+2
  TFR(13) TFR(15) TFR(26) TFR(6)
  a1+=ks1+3u;          b1+=ks1+3u;            // x0+=ks0 (0)
  TFR(17) TFR(29) TFR(16) TFR(24)
  a0+=ks1; a1+=ks2+4u; b0+=ks1; b1+=ks2+4u;
  TFR(13) TFR(15) TFR(26) TFR(6)
  a0+=ks2; a1+=5u;     b0+=ks2; b1+=5u;       // ks0+5
#undef TFR
  uint32_t Ya = ((a0 ^ a1) >> 9) + 0x3f808000u;   // bf16 bits in [31:16], RHU rounding
  uint32_t Yb = ((b0 ^ b1) >> 9) + 0x3f808000u;
#if __has_builtin(__builtin_amdgcn_perm)
  return __builtin_amdgcn_perm(Ya, Yb, 0x03020706u);  // {Yb.hi16, Ya.hi16}
#else
  return (Yb & 0xffff0000u) | (Ya >> 16);
#endif
}

__device__ __forceinline__ float softplus_fast(float x){
  return fmaxf(x,0.f) + __logf(1.f + __expf(-fabsf(x)));
}

__device__ __forceinline__ short f2bf(float f){   // fp32 -> bf16 RNE
  uint32_t u = __float_as_uint(f);
  u += 0x7fffu + ((u>>16)&1u);
  return (short)(u>>16);
}

__device__ __forceinline__ float bf_round(float f){   // fp32 -> bf16 -> fp32
  uint32_t u = __float_as_uint(f);
  u += 0x7fffu + ((u>>16)&1u);
  u &= 0xffff0000u;
  return __uint_as_float(u);
}

// ---------------- K0: embeddings -> transposed bf16 hvT image (coalesced) -----------
// R21: 32-position embed tiles (531 blocks). R22: sc4 stored as 4 SoA planes
// (dg | dg2 | dl | dl2, each NP_ floats) so k1's staging reads are coalesced
// (was 4B lanes at 16B stride, 4x over-fetch). Layout-only, bit-identical.
__global__ __launch_bounds__(256) void k0_embed(
    const int* __restrict__ etype, const float* __restrict__ etime,
    const float* __restrict__ Wt,  const float* __restrict__ temb,
    const float* __restrict__ Wg,  const float* __restrict__ Wl,
    const float* __restrict__ Wn,  const float* __restrict__ Win,
    const float* __restrict__ Wpred,
    uint16_t* __restrict__ hvT, float* __restrict__ sc4, float* __restrict__ outmean,
    uint16_t* __restrict__ wbf, uint16_t* __restrict__ wd, float* __restrict__ rs){
  int blk = blockIdx.x, tid = threadIdx.x;
  if (blk < EBLK){
    __shared__ __align__(16) uint16_t tile[HPAD*EPOS];   // 9216 B
    __shared__ float tvec[EPOS];
    int b = blk >> 4, l0 = (blk & 15)*EPOS;
    int base = b*L_ + l0;
    if (tid < EPOS) tvec[tid] = etime[base + tid];
    __syncthreads();
    const float M = -0.07195578414202429f;  // -ln(10000)/128
    #pragma unroll
    for (int rep = 0; rep < 8; ++rep){      // 64 k x 32 p = 2048 elems
      int idx = rep*256 + tid;
      int k = idx >> 5, p = idx & (EPOS-1);
      float dterm = __expf((float)(2*k) * M);
      float ang = (float)(l0 + p) * dterm + tvec[p] * Wt[k];
      float sv, cv;
      sincosf(ang, &sv, &cv);
      tile[k*EPOS + p]      = (uint16_t)f2bf(sv);
      tile[(64+k)*EPOS + p] = (uint16_t)f2bf(cv);
    }
    if (tid < 128){                          // type rows 128..131 x 32 p
      int r = 128 + (tid >> 5), p = tid & (EPOS-1);
      int et = etype[base + p];
      tile[r*EPOS + p] = (uint16_t)f2bf(temb[et*4 + (r-128)]);
    }
    // pad rows 132..143 zero (12 rows x 32)
    for (int e = tid; e < 12*EPOS; e += 256)
      tile[(H_ + (e >> 5))*EPOS + (e & (EPOS-1))] = 0;
    if (tid < EPOS){
      int bl = base + tid;
      int et = etype[bl];
      float t0 = temb[et*4+0], t1 = temb[et*4+1], t2 = temb[et*4+2], t3 = temb[et*4+3];
      sc4[bl]          = t0*Wg[0]+t1*Wg[1]+t2*Wg[2]+t3*Wg[3];  // dg  (j-side)
      sc4[NP_ + bl]    = t0*Wg[4]+t1*Wg[5]+t2*Wg[6]+t3*Wg[7];  // dg2 (i-side)
      sc4[2*NP_ + bl]  = t0*Wl[0]+t1*Wl[1]+t2*Wl[2]+t3*Wl[3];  // dl
      sc4[3*NP_ + bl]  = t0*Wl[4]+t1*Wl[5]+t2*Wl[6]+t3*Wl[7];  // dl2
      outmean[bl] = 0.f;                                        // zero for k4 atomics
    }
    __syncthreads();
    // writeout: 144 rows x 64B = 576 x 16B chunks
    for (int e = tid; e < HPAD*4; e += 256){
      int r = e >> 2, c = e & 3;
      ((uint4v*)(hvT + ((size_t)b*HPAD + r)*L_ + l0))[c] = ((const uint4v*)(tile + r*EPOS))[c];
    }
  } else {
    int pb = blk - EBLK;               // 0..18
    if (pb < 9){                       // W_noise bf16 image + rowsum(bf16 W)
      for (int e = tid; e < 16*KSTR; e += 256){
        int r = e / KSTR, k = e - r*KSTR;
        int n = pb*16 + r;
        uint16_t v = 0;
        if (n < H_ && k < H_) v = (uint16_t)f2bf(Wn[n*H_ + k]);
        wbf[n*KSTR + k] = v;
      }
      if (tid < 16){
        int n = pb*16 + tid;
        if (n < H_){
          float s = 0.f;
          const float* row = Wn + (size_t)n*H_;
          #pragma unroll 4
          for (int k = 0; k < H_; ++k) s += bf_round(row[k]);
          rs[n] = s;
        }
      }
    } else {                           // [Win; Wpred] bf16 image
      int rb = pb - 9;                 // 0..9
      for (int e = tid; e < 16*KSTR; e += 256){
        int r = e / KSTR, k = e - r*KSTR;
        int n = rb*16 + r;
        uint16_t v = 0;
        if (k < H_){
          if (n < H_)          v = (uint16_t)f2bf(Win[n*H_ + k]);
          else if (n < H_+NT_) v = (uint16_t)f2bf(Wpred[(n-H_)*H_ + k]);
        }
        wd[n*KSTR + k] = v;
      }
    }
  }
}

// ---------------- K1: attention flash-tile + LN + fused decoder --------------------
// R22: GRID TRANSPOSE for CU load balance. Old id = i_tile + 32*b: blocks on a
// CU differ by 256 -> i_tile == const per CU -> CUs that drew i_tile=31 ran 4x
// the work of i_tile=0 CUs; k1 dur = heaviest-CU time (why R7's avg-work cut
// was invisible). New id = b + 32*i_tile: per-CU i_tiles {x,x+8,x+16,x+24} ->
// uniform per-CU work at the average (~10/16 of max).
// R20: causal truncation (KTM4 k-tiles). Decoder writes cvec - rs.
__global__ __launch_bounds__(256) void k1_attn(
    const float* __restrict__ etime, const float* __restrict__ sc4,
    const uint16_t* __restrict__ hvT, const uint16_t* __restrict__ wd,
    const float* __restrict__ bgp, const float* __restrict__ blp,
    const float* __restrict__ gamma, const float* __restrict__ beta,
    const float* __restrict__ rs,
    float* __restrict__ cvec, float* __restrict__ outp){
  __shared__ __align__(16) uint16_t scb[ITILE*SCSTR];
  __shared__ float jt[L_], jg[L_], jl[L_];
  __shared__ float rt[ITILE], rg[ITILE], rl[ITILE];
  __shared__ __align__(16) float hid[ITILE*HIDS];
  __shared__ __align__(16) uint16_t hnl[ITILE*HNLS];
  __shared__ float logit[ITILE*NT_];
  __shared__ float mur[ITILE], rsr[ITILE];
  int b = blockIdx.x, i0 = blockIdx.y*ITILE, base = b*L_;   // R22: transposed
  int tid = threadIdx.x;
  float bg = bgp[0], blv = blp[0];
  int KTM4 = (((i0 + 14) >> 5) + 4) & ~3;   // 4..16 k-tiles actually needed (rounded to 4)
  int JMAX4 = KTM4 << 5;                    // 128..512
  for (int j = tid; j < L_; j += 256){
    jt[j] = etime[base+j];
    jg[j] = sc4[base+j];            // dg plane (SoA, coalesced)
    jl[j] = sc4[2*NP_ + base+j];    // dl plane
  }
  if (tid < ITILE){
    rt[tid] = etime[base+i0+tid];
    rg[tid] = sc4[NP_   + base+i0+tid];   // dg2
    rl[tid] = sc4[3*NP_ + base+i0+tid];   // dl2
  }
  __syncthreads();
  // phase 1: score tile, truncated at JMAX4 (j >= JMAX4 never read by MFMA)
  for (int e = tid; e < ITILE*L_; e += 256){
    int r = e >> 9, j = e & (L_-1);
    if (j >= JMAX4) continue;                 // wave-uniform skip
    float v = 0.f;
    if (j < i0 + r){
      float gate = __frcp_rn(1.f + __expf(-(jg[j] + rg[r] + bg)));
      float ls   = softplus_fast(jl[j] + rl[r] + blv) + 1e-6f;
      float d    = rt[r] - jt[j];
      float t2   = 2.f*ls*ls;
      v = gate * t2 * __frcp_rn(t2 + d*d);
    }
    scb[r*SCSTR + j] = (uint16_t)f2bf(v);
  }
  __syncthreads();
  // phase 2: hidden[16][H] = scores @ hv  (MFMA 16x16x32, B from hvT short8)
  int wave = tid>>6, lane = tid&63, q = lane>>4, col = lane&15;
  for (int nt = wave; nt < NTIL; nt += 4){
    int n = nt*16 + col;
    const uint16_t* bT = hvT + ((size_t)b*HPAD + n)*L_;   // 144 rows, pad rows zero
    float4v acc = {0.f,0.f,0.f,0.f};
    if (KTM4 == 16){
      // heavy blocks: R13 path -- all 16 independent B-loads in flight
      short8 bfr[16];
      #pragma unroll
      for (int kt = 0; kt < 16; ++kt)
        bfr[kt] = *(const short8*)&bT[kt*32 + q*8];
      #pragma unroll
      for (int kt = 0; kt < 16; ++kt){
        short8 af = *(const short8*)&scb[col*SCSTR + kt*32 + q*8];
        acc = __builtin_amdgcn_mfma_f32_16x16x32_bf16(af, bfr[kt], acc, 0, 0, 0);
      }
    } else {
      for (int ktc = 0; ktc < KTM4; ktc += 4){
        const uint16_t* bc = bT + ktc*32 + q*8;
        short8 b0 = *(const short8*)&bc[0];
        short8 b1 = *(const short8*)&bc[32];
        short8 b2 = *(const short8*)&bc[64];
        short8 b3 = *(const short8*)&bc[96];
        const uint16_t* ac = scb + col*SCSTR + ktc*32 + q*8;
        acc = __builtin_amdgcn_mfma_f32_16x16x32_bf16(*(const short8*)&ac[0],  b0, acc, 0, 0, 0);
        acc = __builtin_amdgcn_mfma_f32_16x16x32_bf16(*(const short8*)&ac[32], b1, acc, 0, 0, 0);
        acc = __builtin_amdgcn_mfma_f32_16x16x32_bf16(*(const short8*)&ac[64], b2, acc, 0, 0, 0);
        acc = __builtin_amdgcn_mfma_f32_16x16x32_bf16(*(const short8*)&ac[96], b3, acc, 0, 0, 0);
      }
    }
    if (n < H_){
      #pragma unroll
      for (int rr = 0; rr < 4; ++rr)
        hid[(q*4+rr)*HIDS + n] = acc[rr];    // C/D: row=q*4+rr, col=n
    }
  }
  __syncthreads();
  // LayerNorm stats
  #pragma unroll
  for (int rr = 0; rr < 4; ++rr){
    int r = wave*4 + rr;
    float x0 = hid[r*HIDS + lane];
    float x1 = hid[r*HIDS + 64 + lane];
    float x2 = (lane<4) ? hid[r*HIDS + 128 + lane] : 0.f;
    float s1 = x0+x1+x2, s2 = x0*x0+x1*x1+x2*x2;
    #pragma unroll
    for (int m=32; m; m>>=1){ s1 += __shfl_xor(s1, m, 64); s2 += __shfl_xor(s2, m, 64); }
    if (lane == 0){
      float mu = s1 * (1.f/132.f);
      float var = s2 * (1.f/132.f) - mu*mu;
      mur[r] = mu; rsr[r] = rsqrtf(var + 1e-6f);
    }
  }
  __syncthreads();
  if (tid < HNLS){
    if (tid < H_){
      float g = gamma[tid], be = beta[tid];
      #pragma unroll 4
      for (int r = 0; r < ITILE; ++r)
        hnl[r*HNLS + tid] = (uint16_t)f2bf((hid[r*HIDS+tid]-mur[r])*rsr[r]*g + be);
    } else {
      #pragma unroll 4
      for (int r = 0; r < ITILE; ++r) hnl[r*HNLS + tid] = 0;
    }
  }
  __syncthreads();
  // fused decoder: hn(16x132) @ wd(152x132)^T -> (cvec - rs) + logits
  short8 afr[KCH];
  #pragma unroll
  for (int kc = 0; kc < KCH; ++kc)
    afr[kc] = *(const short8*)&hnl[col*HNLS + kc*32 + q*8];   // A[m=col][k]
  for (int nt = wave; nt < NTIL3; nt += 4){
    float4v acc = {0.f,0.f,0.f,0.f};
    const short8* bp = (const short8*)&wd[(nt*16+col)*KSTR];
    #pragma unroll
    for (int kc = 0; kc < KCH; ++kc){
      // kc=4,q>0 reads past wd row end: A zero at k>=132 -- harmless
      short8 bfr = bp[kc*4 + q];
      acc = __builtin_amdgcn_mfma_f32_16x16x32_bf16(afr[kc], bfr, acc, 0, 0, 0);
    }
    int n = nt*16 + col;
    #pragma unroll
    for (int rr = 0; rr < 4; ++rr){
      int lr = q*4 + rr;
      if (n < H_)            cvec[(size_t)(base+i0+lr)*H_ + n] = acc[rr] - rs[n];
      else if (n < H_+NT_)   logit[lr*NT_ + (n-H_)] = acc[rr];
    }
  }
  __syncthreads();
  if (tid < ITILE){
    float mx = -1e30f;
    #pragma unroll
    for (int j=0;j<NT_;++j) mx = fmaxf(mx, logit[tid*NT_+j]);
    float ex[NT_]; float ssum = 0.f;
    #pragma unroll
    for (int j=0;j<NT_;++j){ ex[j] = __expf(logit[tid*NT_+j]-mx); ssum += ex[j]; }
    float inv = __frcp_rn(ssum);
    #pragma unroll
    for (int j=0;j<NT_;++j)
      outp[(size_t)(B_*L_) + (size_t)(base+i0+tid)*NT_ + j] = ex[j]*inv;
  }
}

// ---------------- K4: GAN sampler (R8 best, unchanged) -----------------------------
__global__ __launch_bounds__(512, 4) void k4_sampler(
    const uint16_t* __restrict__ wbf, const float* __restrict__ cvec,
    const float* __restrict__ wt, float* __restrict__ outmean){
  __shared__ __align__(16) short Wlds[WBF_N + 32];  // +32: slack for kc=4 tail over-read
  __shared__ float wtlds[HPAD];
  __shared__ float part[128];
  int tid = threadIdx.x, lane = tid & 63;
  int l0 = blockIdx.x*16, b = blockIdx.y, sch = blockIdx.z;
  int bl0 = b*L_ + l0;

  {   // stage W (incl. slack words -- keeps kc=4 over-read finite): 2452 x 16B
    const uint4v* g = (const uint4v*)wbf;
    uint4v* l = (uint4v*)Wlds;
    for (int idx = tid; idx < (WBF_N+32)/8; idx += 512) l[idx] = g[idx];
  }
  if (tid < HPAD) wtlds[tid] = (tid < H_) ? wt[tid] : 0.f;
  if (tid < 128) part[tid] = 0.f;
  __syncthreads();

  int wave = tid >> 6;
  int q = lane >> 4, col = lane & 15;
  int s = sch*8 + wave;
  if (s < SMP_){
    uint32_t fbase = (uint32_t)(bl0 + col)*(uint32_t)(SMP_*H_)
                   + (uint32_t)s*(uint32_t)H_;
    uint32_t fbq = fbase + (uint32_t)(q*8);
    uint4v afu[KCH];
    #pragma unroll
    for (int kc = 0; kc < 4; ++kc){
      #pragma unroll
      for (int t = 0; t < 4; ++t)
        afu[kc][t] = tfpair(fbq + (uint32_t)(kc*32 + 2*t),
                            fbq + (uint32_t)(kc*32 + 2*t + 1));
    }
    {   // tail features 128..131: one full-wave stream (q even:128/129, q odd:130/131)
      uint32_t ft = fbase + 128u + (uint32_t)((q & 1)*2);
      uint32_t w  = tfpair(ft, ft + 1u);
      uint32_t wo = (uint32_t)__shfl_xor((int)w, 16, 64);
      uint4v a4 = {0u,0u,0u,0u};
      if (q == 0){ a4[0] = w; a4[1] = wo; }
      afu[4] = a4;
    }
    const float* cbase = cvec + (size_t)(bl0 + q*4)*H_;
    float racc0=0.f, racc1=0.f, racc2=0.f, racc3=0.f;
    for (int nt = 0; nt < NTIL; ++nt){
      float4v acc = {0.f,0.f,0.f,0.f};
      const short8* bp = (const short8*)&Wlds[(nt*16+col)*KSTR];
      #pragma unroll
      for (int kc = 0; kc < KCH; ++kc){
        short8 bfr = bp[kc*4 + q];
        acc = __builtin_amdgcn_mfma_f32_16x16x32_bf16(
                 __builtin_bit_cast(short8, afu[kc]), bfr, acc, 0, 0, 0);
      }
      int n = nt*16 + col;
      float wv = wtlds[n];
      const float* cb = cbase + n;
      racc0 += fmaxf(acc[0] + cb[0*H_], 0.f)*wv;
      racc1 += fmaxf(acc[1] + cb[1*H_], 0.f)*wv;
      racc2 += fmaxf(acc[2] + cb[2*H_], 0.f)*wv;
      racc3 += fmaxf(acc[3] + cb[3*H_], 0.f)*wv;
    }
    #pragma unroll
    for (int m = 1; m < 16; m <<= 1){
      racc0 += __shfl_xor(racc0, m, 64);
      racc1 += __shfl_xor(racc1, m, 64);
      racc2 += __shfl_xor(racc2, m, 64);
      racc3 += __shfl_xor(racc3, m, 64);
    }
    if (col == 0){
      part[wave*16 + q*4 + 0] = 0.02f * softplus_fast(racc0);
      part[wave*16 + q*4 + 1] = 0.02f * softplus_fast(racc1);
      part[wave*16 + q*4 + 2] = 0.02f * softplus_fast(racc2);
      part[wave*16 + q*4 + 3] = 0.02f * softplus_fast(racc3);
    }
  }
  __syncthreads();
  if (tid < 16){
    float v = 0.f;
    #pragma unroll
    for (int w = 0; w < 8; ++w) v += part[w*16 + tid];
    atomicAdd(&outmean[bl0 + tid], v);
  }
}

// ---------------- launch ----------------
extern "C" void kernel_launch(void* const* d_in, const int* in_sizes, int n_in,
                              void* d_out, int out_size, void* d_ws, size_t ws_size,
                              hipStream_t stream){
  const int*   etype = (const int*)  d_in[0];
  const float* etime = (const float*)d_in[1];
  const float* Wt    = (const float*)d_in[3];
  const float* temb  = (const float*)d_in[4];
  const float* Wg    = (const float*)d_in[5];
  const float* bgp   = (const float*)d_in[6];
  const float* Wl    = (const float*)d_in[7];
  const float* blp   = (const float*)d_in[8];
  const float* gamma = (const float*)d_in[9];
  const float* beta  = (const float*)d_in[10];
  const float* Win   = (const float*)d_in[11];
  const float* Wn    = (const float*)d_in[12];
  const float* wtm   = (const float*)d_in[13];
  const float* Wpred = (const float*)d_in[14];
  float* out = (float*)d_out;

  uint16_t* hvT   = (uint16_t*)d_ws;                        // 32*144*512 shorts
  float*    sc4   = (float*)(hvT + (size_t)B_*HPAD*L_);     // 4 SoA planes x NP_ floats
  float*    cvec  = sc4 + (size_t)NP_*4;                    // 16384*132 floats
  float*    rs    = cvec + (size_t)NP_*H_;                  // 132 (+pad to 256)
  uint16_t* wbf   = (uint16_t*)(rs + 256);                  // WBF_N shorts
  uint16_t* wd    = wbf + (size_t)WBF_N;                    // WDROW*KSTR shorts

  k0_embed  <<<dim3(EBLK+19),  dim3(256), 0, stream>>>(etype, etime, Wt, temb, Wg, Wl,
                                                       Wn, Win, Wpred, hvT, sc4, out, wbf, wd, rs);
  k1_attn   <<<dim3(32,32),    dim3(256), 0, stream>>>(etime, sc4, hvT, wd, bgp, blp,
                                                       gamma, beta, rs, cvec, out);
  k4_sampler<<<dim3(32,32,7),  dim3(512), 0, stream>>>(wbf, cvec, wtm, out);
}